// Round 1
// baseline (2964.976 us; speedup 1.0000x reference)
//
#include <hip/hip_runtime.h>

// Problem constants
#define B_    64
#define C_    256
#define H_    32
#define W_    32
#define K_    1024
#define D_    256
#define HW_   1024          // H*W
#define N_    65536         // B*H*W
#define NELEM 16777216      // B*C*H*W
#define DECAY_ 0.99f
#define OMD_   0.01f        // 1-DECAY
#define EPS_   1e-5f
#define TAU_   0.05f        // fp64-rescan margin

// d_out float offsets
#define OFF_LOSS    16777216
#define OFF_ENT     16777217
#define OFF_ENC     16777218   // 8B-aligned only -> float2 stores
#define OFF_CLUSTER 83886082
#define OFF_NEWW    83887106
#define OFF_NEWEMB  84149250

// ws layout (4-byte units): idx[65536] | counts[1024] | flagc | losssum | flaglist[65536] | enorm[1024]

__global__ __launch_bounds__(64) void k_enorm(const float* __restrict__ emb, float* __restrict__ enorm) {
    int k = blockIdx.x;
    float4 v = ((const float4*)(emb + (size_t)k * D_))[threadIdx.x];
    float s = v.x * v.x + v.y * v.y + v.z * v.z + v.w * v.w;
    #pragma unroll
    for (int off = 32; off > 0; off >>= 1) s += __shfl_down(s, off);
    if (threadIdx.x == 0) enorm[k] = s;
}

__global__ __launch_bounds__(256) void k_zero(float* __restrict__ dw, int* __restrict__ small_) {
    int g = blockIdx.x * 256 + threadIdx.x;
    if (g < K_ * D_) dw[g] = 0.0f;
    if (g < 1026) small_[g] = 0;   // counts[1024] + flagcount + losssum
}

// Distance argmin: per row track best/second-best of (||e||^2 - 2 x.e); flag tight margins.
__global__ __launch_bounds__(256) void k_argmin(
    const float* __restrict__ inp, const float* __restrict__ emb,
    const float* __restrict__ enorm, int* __restrict__ idx_out,
    int* __restrict__ flagcount, int* __restrict__ flaglist)
{
    __shared__ float xs[32][132];   // xs[d][row], +4 pad
    __shared__ float es[32][132];   // es[d][cluster-in-tile]
    __shared__ float r_v1[128][17];
    __shared__ float r_v2[128][17];
    __shared__ int   r_i1[128][17];

    const int tid = threadIdx.x;
    const int tx = tid & 15;
    const int ty = tid >> 4;
    const int rowbase = blockIdx.x * 128;
    const int b = rowbase >> 10;
    const int noff = rowbase & 1023;
    // flat[n][d] = inp[b][d][n%1024]  (NCHW layout => d-major, contiguous over n)
    const float* xbase = inp + (size_t)b * (C_ * HW_) + noff;

    float b1v[8], b2v[8];
    int b1i[8];
    #pragma unroll
    for (int i = 0; i < 8; ++i) { b1v[i] = 3.0e38f; b2v[i] = 3.0e38f; b1i[i] = 0; }

    for (int ct = 0; ct < K_; ct += 128) {
        float acc[8][8];
        #pragma unroll
        for (int i = 0; i < 8; ++i) {
            #pragma unroll
            for (int j = 0; j < 8; ++j) acc[i][j] = 0.0f;
        }
        for (int dc = 0; dc < D_; dc += 32) {
            __syncthreads();
            {
                const int nl = (tid & 31) * 4;
                const int dl0 = tid >> 5;
                #pragma unroll
                for (int p = 0; p < 4; ++p) {
                    int dl = dl0 + p * 8;
                    float4 v = *(const float4*)(xbase + (size_t)(dc + dl) * HW_ + nl);
                    *(float4*)&xs[dl][nl] = v;
                }
                const int d4 = (tid & 7) * 4;
                const int kl0 = tid >> 3;
                #pragma unroll
                for (int p = 0; p < 4; ++p) {
                    int kl = kl0 + p * 32;
                    float4 v = *(const float4*)(emb + (size_t)(ct + kl) * D_ + dc + d4);
                    es[d4 + 0][kl] = v.x;
                    es[d4 + 1][kl] = v.y;
                    es[d4 + 2][kl] = v.z;
                    es[d4 + 3][kl] = v.w;
                }
            }
            __syncthreads();
            #pragma unroll 8
            for (int d = 0; d < 32; ++d) {
                float4 xa0 = *(const float4*)&xs[d][ty * 8];
                float4 xa1 = *(const float4*)&xs[d][ty * 8 + 4];
                float4 eb0 = *(const float4*)&es[d][tx * 4];
                float4 eb1 = *(const float4*)&es[d][64 + tx * 4];
                float xa[8] = {xa0.x, xa0.y, xa0.z, xa0.w, xa1.x, xa1.y, xa1.z, xa1.w};
                float eb[8] = {eb0.x, eb0.y, eb0.z, eb0.w, eb1.x, eb1.y, eb1.z, eb1.w};
                #pragma unroll
                for (int i = 0; i < 8; ++i) {
                    #pragma unroll
                    for (int j = 0; j < 8; ++j)
                        acc[i][j] = fmaf(xa[i], eb[j], acc[i][j]);
                }
            }
        }
        #pragma unroll
        for (int i = 0; i < 8; ++i) {
            #pragma unroll
            for (int j = 0; j < 8; ++j) {
                int kg = ct + ((j < 4) ? (tx * 4 + j) : (64 + tx * 4 + (j - 4)));  // ascending per thread
                float v = enorm[kg] - 2.0f * acc[i][j];
                if (v < b1v[i]) { b2v[i] = b1v[i]; b1v[i] = v; b1i[i] = kg; }
                else if (v < b2v[i]) b2v[i] = v;
            }
        }
    }
    __syncthreads();
    #pragma unroll
    for (int i = 0; i < 8; ++i) {
        int r = ty * 8 + i;
        r_v1[r][tx] = b1v[i];
        r_v2[r][tx] = b2v[i];
        r_i1[r][tx] = b1i[i];
    }
    __syncthreads();
    if (tid < 128) {
        float B1 = 3.0e38f, B2 = 3.0e38f;
        int Bi = 0;
        #pragma unroll
        for (int t = 0; t < 16; ++t) {
            float v1 = r_v1[tid][t], v2 = r_v2[tid][t];
            int i1 = r_i1[tid][t];
            if (v1 < B1 || (v1 == B1 && i1 < Bi)) {
                B2 = fminf(fminf(B1, B2), v2);
                B1 = v1; Bi = i1;
            } else {
                B2 = fminf(B2, v1);
            }
        }
        idx_out[rowbase + tid] = Bi;
        if (B2 - B1 < TAU_) {
            int p = atomicAdd(flagcount, 1);
            flaglist[p] = rowbase + tid;
        }
    }
}

// Exact fp64 rescan of flagged (near-tie) rows -> true argmin.
__global__ __launch_bounds__(256) void k_rescan(
    const float* __restrict__ inp, const float* __restrict__ emb,
    const int* __restrict__ flagcount, const int* __restrict__ flaglist,
    int* __restrict__ idx_out)
{
    __shared__ double xd[256];
    __shared__ double sv[256];
    __shared__ int si[256];
    const int tid = threadIdx.x;
    const int nflag = *flagcount;
    for (int f = blockIdx.x; f < nflag; f += gridDim.x) {
        int n = flaglist[f];
        int b = n >> 10, nn = n & 1023;
        xd[tid] = (double)inp[(size_t)b * (C_ * HW_) + (size_t)tid * HW_ + nn];
        __syncthreads();
        double bv = 1e300; int bi = 0;
        for (int k = tid; k < K_; k += 256) {
            const float* ep = emb + (size_t)k * D_;
            double dot = 0.0, en = 0.0;
            for (int d = 0; d < D_; ++d) {
                double e = (double)ep[d];
                dot = fma(xd[d], e, dot);
                en  = fma(e, e, en);
            }
            double v = en - 2.0 * dot;
            if (v < bv) { bv = v; bi = k; }
        }
        sv[tid] = bv; si[tid] = bi;
        __syncthreads();
        for (int s = 128; s > 0; s >>= 1) {
            if (tid < s) {
                if (sv[tid + s] < sv[tid] || (sv[tid + s] == sv[tid] && si[tid + s] < si[tid])) {
                    sv[tid] = sv[tid + s]; si[tid] = si[tid + s];
                }
            }
            __syncthreads();
        }
        if (tid == 0) idx_out[n] = si[0];
        __syncthreads();
    }
}

// One-hot encodings, float2 stores (region only 8B aligned).
__global__ __launch_bounds__(256) void k_enc(const int* __restrict__ idx, float2* __restrict__ enc) {
    const int base = blockIdx.x * 2048;
    #pragma unroll
    for (int it = 0; it < 8; ++it) {
        int f = base + it * 256 + threadIdx.x;
        int n = f >> 9;
        int k0 = (f & 511) * 2;
        int ki = idx[n];
        float2 v;
        v.x = (k0 == ki) ? 1.0f : 0.0f;
        v.y = (k0 + 1 == ki) ? 1.0f : 0.0f;
        enc[f] = v;
    }
}

// quantized straight-through output (NCHW) + commitment-loss partial sum
__global__ __launch_bounds__(256) void k_quant(
    const float* __restrict__ inp, const float* __restrict__ emb,
    const int* __restrict__ idx, float* __restrict__ outp, float* __restrict__ losssum)
{
    __shared__ float red[256];
    const int tid = threadIdx.x;
    float s = 0.0f;
    const int base = blockIdx.x * 1024;
    #pragma unroll
    for (int it = 0; it < 4; ++it) {
        int g = base + it * 256 + tid;
        int o = g << 2;
        int b = o >> 18;
        int c = (o >> 10) & 255;
        int hw = o & 1023;
        int n = (b << 10) + hw;
        float4 x = ((const float4*)inp)[g];
        int4 ki = *(const int4*)(idx + n);
        float q0 = emb[(size_t)ki.x * D_ + c];
        float q1 = emb[(size_t)ki.y * D_ + c];
        float q2 = emb[(size_t)ki.z * D_ + c];
        float q3 = emb[(size_t)ki.w * D_ + c];
        float d0 = q0 - x.x, d1 = q1 - x.y, d2 = q2 - x.z, d3 = q3 - x.w;
        float4 r = make_float4(x.x + d0, x.y + d1, x.z + d2, x.w + d3);  // matches ref x+(q-x)
        ((float4*)outp)[g] = r;
        s += d0 * d0 + d1 * d1 + d2 * d2 + d3 * d3;
    }
    red[tid] = s;
    __syncthreads();
    for (int t = 128; t > 0; t >>= 1) {
        if (tid < t) red[tid] += red[tid + t];
        __syncthreads();
    }
    if (tid == 0) atomicAdd(losssum, red[0]);
}

__global__ __launch_bounds__(256) void k_hist(const int* __restrict__ idx, int* __restrict__ counts) {
    __shared__ int h[1024];
    const int tid = threadIdx.x;
    #pragma unroll
    for (int j = 0; j < 4; ++j) h[tid + j * 256] = 0;
    __syncthreads();
    #pragma unroll
    for (int j = 0; j < 4; ++j) {
        int n = blockIdx.x * 1024 + j * 256 + tid;
        atomicAdd(&h[idx[n]], 1);
    }
    __syncthreads();
    #pragma unroll
    for (int j = 0; j < 4; ++j) {
        int v = h[tid + j * 256];
        if (v) atomicAdd(&counts[tid + j * 256], v);
    }
}

// dw scatter: coalesced stream of inputs (d-major), atomicAdd into new_ema_w region (pre-zeroed)
__global__ __launch_bounds__(256) void k_dw(const float* __restrict__ inp, const int* __restrict__ idx,
                                            float* __restrict__ dw) {
    int g = blockIdx.x * 256 + threadIdx.x;
    int o = g << 2;
    int b = o >> 18;
    int d = (o >> 10) & 255;
    int nn = o & 1023;
    float4 x = ((const float4*)inp)[g];
    int4 ki = *(const int4*)(idx + (b << 10) + nn);
    atomicAdd(&dw[(size_t)ki.x * D_ + d], x.x);
    atomicAdd(&dw[(size_t)ki.y * D_ + d], x.y);
    atomicAdd(&dw[(size_t)ki.z * D_ + d], x.z);
    atomicAdd(&dw[(size_t)ki.w * D_ + d], x.w);
}

__global__ __launch_bounds__(1024) void k_cluster(
    const float* __restrict__ ema_cs, const int* __restrict__ counts,
    const float* __restrict__ losssum, float* __restrict__ out_cluster,
    float* __restrict__ out_loss, float* __restrict__ out_ent)
{
    __shared__ float red[1024];
    const int k = threadIdx.x;
    float cnt = (float)counts[k];
    float raw = ema_cs[k] * DECAY_ + OMD_ * cnt;
    red[k] = raw;
    __syncthreads();
    for (int t = 512; t > 0; t >>= 1) {
        if (k < t) red[k] += red[k + t];
        __syncthreads();
    }
    float nsum = red[0];
    __syncthreads();
    float clv = (raw + EPS_) / (nsum + 1024.0f * EPS_) * nsum;
    out_cluster[k] = clv;
    float p = cnt * (1.0f / 65536.0f);
    red[k] = p * logf(p + 1e-10f);
    __syncthreads();
    for (int t = 512; t > 0; t >>= 1) {
        if (k < t) red[k] += red[k + t];
        __syncthreads();
    }
    if (k == 0) {
        out_ent[0] = -red[0];
        out_loss[0] = 0.25f * losssum[0] * (1.0f / 16777216.0f);
    }
}

__global__ __launch_bounds__(256) void k_fin(
    const float* __restrict__ ema_w, const float* __restrict__ cluster,
    float* __restrict__ neww, float* __restrict__ newemb)
{
    int g = blockIdx.x * 256 + threadIdx.x;
    int k = g >> 8;
    float w = ema_w[g] * DECAY_ + OMD_ * neww[g];   // neww currently holds dw
    neww[g] = w;
    newemb[g] = w / cluster[k];
}

extern "C" void kernel_launch(void* const* d_in, const int* in_sizes, int n_in,
                              void* d_out, int out_size, void* d_ws, size_t ws_size,
                              hipStream_t stream)
{
    const float* inp    = (const float*)d_in[0];
    const float* emb    = (const float*)d_in[1];
    const float* ema_cs = (const float*)d_in[2];
    const float* ema_w  = (const float*)d_in[3];

    float* out0        = (float*)d_out;
    float* out_loss    = out0 + OFF_LOSS;
    float* out_ent     = out0 + OFF_ENT;
    float* out_enc     = out0 + OFF_ENC;
    float* out_cluster = out0 + OFF_CLUSTER;
    float* out_neww    = out0 + OFF_NEWW;
    float* out_newemb  = out0 + OFF_NEWEMB;

    int*   ws_idx    = (int*)d_ws;
    int*   ws_counts = ws_idx + 65536;
    int*   ws_flagc  = ws_idx + 66560;
    float* ws_loss   = (float*)(ws_idx + 66561);
    int*   ws_flagl  = ws_idx + 66562;
    float* ws_enorm  = (float*)(ws_idx + 132098);

    k_zero  <<<1024, 256, 0, stream>>>(out_neww, ws_counts);
    k_enorm <<<1024, 64, 0, stream>>>(emb, ws_enorm);
    k_argmin<<<512, 256, 0, stream>>>(inp, emb, ws_enorm, ws_idx, ws_flagc, ws_flagl);
    k_rescan<<<256, 256, 0, stream>>>(inp, emb, ws_flagc, ws_flagl, ws_idx);
    k_enc   <<<16384, 256, 0, stream>>>(ws_idx, (float2*)out_enc);
    k_quant <<<4096, 256, 0, stream>>>(inp, emb, ws_idx, out0, ws_loss);
    k_hist  <<<64, 256, 0, stream>>>(ws_idx, ws_counts);
    k_dw    <<<16384, 256, 0, stream>>>(inp, ws_idx, out_neww);
    k_cluster<<<1, 1024, 0, stream>>>(ema_cs, ws_counts, ws_loss, out_cluster, out_loss, out_ent);
    k_fin   <<<1024, 256, 0, stream>>>(ema_w, out_cluster, out_neww, out_newemb);
}

// Round 2
// 1331.465 us; speedup vs baseline: 2.2269x; 2.2269x over previous
//
#include <hip/hip_runtime.h>

// Problem constants
#define B_    64
#define C_    256
#define H_    32
#define W_    32
#define K_    1024
#define D_    256
#define HW_   1024          // H*W
#define N_    65536         // B*H*W
#define NELEM 16777216      // B*C*H*W
#define DECAY_ 0.99f
#define OMD_   0.01f        // 1-DECAY
#define EPS_   1e-5f
#define TAU_   0.05f        // fp64-rescan margin

// d_out float offsets
#define OFF_LOSS    16777216
#define OFF_ENT     16777217
#define OFF_ENC     16777218   // 8B-aligned only -> float2 stores
#define OFF_CLUSTER 83886082
#define OFF_NEWW    83887106   // 8B-aligned only
#define OFF_NEWEMB  84149250

// Scratch inside the (later overwritten) encodings output region:
//   flat[n][d] n-major fp32 at out0 + OFF_ENC + 2   (16B aligned)
//   sorted[65536], offsets[1025], cursor[1024] after it
#define OFF_FLAT    (OFF_ENC + 2)           // 16777220 -> byte ofs % 16 == 0
#define OFF_SORT    (OFF_FLAT + 16777216)

// ws layout (4-byte units): idx[65536] | counts[1024] | flagc | losssum | flaglist[65536] | enorm[1024]

__global__ __launch_bounds__(64) void k_enorm(const float* __restrict__ emb, float* __restrict__ enorm) {
    int k = blockIdx.x;
    float4 v = ((const float4*)(emb + (size_t)k * D_))[threadIdx.x];
    float s = v.x * v.x + v.y * v.y + v.z * v.z + v.w * v.w;
    #pragma unroll
    for (int off = 32; off > 0; off >>= 1) s += __shfl_down(s, off);
    if (threadIdx.x == 0) enorm[k] = s;
}

__global__ __launch_bounds__(256) void k_zero(int* __restrict__ small_) {
    int g = blockIdx.x * 256 + threadIdx.x;
    if (g < 1026) small_[g] = 0;   // counts[1024] + flagcount + losssum
}

// Distance argmin: per row track best/second-best of (||e||^2 - 2 x.e); flag tight margins.
// Side product: writes flat[n][d] (n-major) to scratch for the dw gather.
__global__ __launch_bounds__(256) void k_argmin(
    const float* __restrict__ inp, const float* __restrict__ emb,
    const float* __restrict__ enorm, int* __restrict__ idx_out,
    int* __restrict__ flagcount, int* __restrict__ flaglist,
    float* __restrict__ flatbuf)
{
    __shared__ float xs[32][132];   // xs[d][row], +4 pad
    __shared__ float es[32][132];   // es[d][cluster-in-tile]
    __shared__ float r_v1[128][17];
    __shared__ float r_v2[128][17];
    __shared__ int   r_i1[128][17];

    const int tid = threadIdx.x;
    const int tx = tid & 15;
    const int ty = tid >> 4;
    const int rowbase = blockIdx.x * 128;
    const int b = rowbase >> 10;
    const int noff = rowbase & 1023;
    // flat[n][d] = inp[b][d][n%1024]  (NCHW layout => d-major, contiguous over n)
    const float* xbase = inp + (size_t)b * (C_ * HW_) + noff;

    float b1v[8], b2v[8];
    int b1i[8];
    #pragma unroll
    for (int i = 0; i < 8; ++i) { b1v[i] = 3.0e38f; b2v[i] = 3.0e38f; b1i[i] = 0; }

    for (int ct = 0; ct < K_; ct += 128) {
        float acc[8][8];
        #pragma unroll
        for (int i = 0; i < 8; ++i) {
            #pragma unroll
            for (int j = 0; j < 8; ++j) acc[i][j] = 0.0f;
        }
        for (int dc = 0; dc < D_; dc += 32) {
            __syncthreads();
            {
                const int nl = (tid & 31) * 4;
                const int dl0 = tid >> 5;
                #pragma unroll
                for (int p = 0; p < 4; ++p) {
                    int dl = dl0 + p * 8;
                    float4 v = *(const float4*)(xbase + (size_t)(dc + dl) * HW_ + nl);
                    *(float4*)&xs[dl][nl] = v;
                }
                const int d4 = (tid & 7) * 4;
                const int kl0 = tid >> 3;
                #pragma unroll
                for (int p = 0; p < 4; ++p) {
                    int kl = kl0 + p * 32;
                    float4 v = *(const float4*)(emb + (size_t)(ct + kl) * D_ + dc + d4);
                    es[d4 + 0][kl] = v.x;
                    es[d4 + 1][kl] = v.y;
                    es[d4 + 2][kl] = v.z;
                    es[d4 + 3][kl] = v.w;
                }
            }
            __syncthreads();
            if (ct == 0) {
                // Emit transposed flat rows: 128 rows x 32 d, 64B per thread.
                const int row = tid >> 1;
                const int d0 = (tid & 1) * 16;
                float t0[16];
                #pragma unroll
                for (int j = 0; j < 16; ++j) t0[j] = xs[d0 + j][row];
                float4* dst = (float4*)(flatbuf + (size_t)(rowbase + row) * D_ + dc + d0);
                dst[0] = make_float4(t0[0], t0[1], t0[2], t0[3]);
                dst[1] = make_float4(t0[4], t0[5], t0[6], t0[7]);
                dst[2] = make_float4(t0[8], t0[9], t0[10], t0[11]);
                dst[3] = make_float4(t0[12], t0[13], t0[14], t0[15]);
            }
            #pragma unroll 8
            for (int d = 0; d < 32; ++d) {
                float4 xa0 = *(const float4*)&xs[d][ty * 8];
                float4 xa1 = *(const float4*)&xs[d][ty * 8 + 4];
                float4 eb0 = *(const float4*)&es[d][tx * 4];
                float4 eb1 = *(const float4*)&es[d][64 + tx * 4];
                float xa[8] = {xa0.x, xa0.y, xa0.z, xa0.w, xa1.x, xa1.y, xa1.z, xa1.w};
                float eb[8] = {eb0.x, eb0.y, eb0.z, eb0.w, eb1.x, eb1.y, eb1.z, eb1.w};
                #pragma unroll
                for (int i = 0; i < 8; ++i) {
                    #pragma unroll
                    for (int j = 0; j < 8; ++j)
                        acc[i][j] = fmaf(xa[i], eb[j], acc[i][j]);
                }
            }
        }
        #pragma unroll
        for (int i = 0; i < 8; ++i) {
            #pragma unroll
            for (int j = 0; j < 8; ++j) {
                int kg = ct + ((j < 4) ? (tx * 4 + j) : (64 + tx * 4 + (j - 4)));  // ascending per thread
                float v = enorm[kg] - 2.0f * acc[i][j];
                if (v < b1v[i]) { b2v[i] = b1v[i]; b1v[i] = v; b1i[i] = kg; }
                else if (v < b2v[i]) b2v[i] = v;
            }
        }
    }
    __syncthreads();
    #pragma unroll
    for (int i = 0; i < 8; ++i) {
        int r = ty * 8 + i;
        r_v1[r][tx] = b1v[i];
        r_v2[r][tx] = b2v[i];
        r_i1[r][tx] = b1i[i];
    }
    __syncthreads();
    if (tid < 128) {
        float B1 = 3.0e38f, B2 = 3.0e38f;
        int Bi = 0;
        #pragma unroll
        for (int t = 0; t < 16; ++t) {
            float v1 = r_v1[tid][t], v2 = r_v2[tid][t];
            int i1 = r_i1[tid][t];
            if (v1 < B1 || (v1 == B1 && i1 < Bi)) {
                B2 = fminf(fminf(B1, B2), v2);
                B1 = v1; Bi = i1;
            } else {
                B2 = fminf(B2, v1);
            }
        }
        idx_out[rowbase + tid] = Bi;
        if (B2 - B1 < TAU_) {
            int p = atomicAdd(flagcount, 1);
            flaglist[p] = rowbase + tid;
        }
    }
}

// Exact fp64 rescan of flagged (near-tie) rows -> true argmin.
__global__ __launch_bounds__(256) void k_rescan(
    const float* __restrict__ inp, const float* __restrict__ emb,
    const int* __restrict__ flagcount, const int* __restrict__ flaglist,
    int* __restrict__ idx_out)
{
    __shared__ double xd[256];
    __shared__ double sv[256];
    __shared__ int si[256];
    const int tid = threadIdx.x;
    const int nflag = *flagcount;
    for (int f = blockIdx.x; f < nflag; f += gridDim.x) {
        int n = flaglist[f];
        int b = n >> 10, nn = n & 1023;
        xd[tid] = (double)inp[(size_t)b * (C_ * HW_) + (size_t)tid * HW_ + nn];
        __syncthreads();
        double bv = 1e300; int bi = 0;
        for (int k = tid; k < K_; k += 256) {
            const float* ep = emb + (size_t)k * D_;
            double dot = 0.0, en = 0.0;
            for (int d = 0; d < D_; ++d) {
                double e = (double)ep[d];
                dot = fma(xd[d], e, dot);
                en  = fma(e, e, en);
            }
            double v = en - 2.0 * dot;
            if (v < bv) { bv = v; bi = k; }
        }
        sv[tid] = bv; si[tid] = bi;
        __syncthreads();
        for (int s = 128; s > 0; s >>= 1) {
            if (tid < s) {
                if (sv[tid + s] < sv[tid] || (sv[tid + s] == sv[tid] && si[tid + s] < si[tid])) {
                    sv[tid] = sv[tid + s]; si[tid] = si[tid + s];
                }
            }
            __syncthreads();
        }
        if (tid == 0) idx_out[n] = si[0];
        __syncthreads();
    }
}

__global__ __launch_bounds__(256) void k_hist(const int* __restrict__ idx, int* __restrict__ counts) {
    __shared__ int h[1024];
    const int tid = threadIdx.x;
    #pragma unroll
    for (int j = 0; j < 4; ++j) h[tid + j * 256] = 0;
    __syncthreads();
    #pragma unroll
    for (int j = 0; j < 4; ++j) {
        int n = blockIdx.x * 1024 + j * 256 + tid;
        atomicAdd(&h[idx[n]], 1);
    }
    __syncthreads();
    #pragma unroll
    for (int j = 0; j < 4; ++j) {
        int v = h[tid + j * 256];
        if (v) atomicAdd(&counts[tid + j * 256], v);
    }
}

// Exclusive prefix scan of counts -> offsets[1025], cursor copy.
__global__ __launch_bounds__(1024) void k_scan(const int* __restrict__ counts,
                                               int* __restrict__ offsets, int* __restrict__ cursor) {
    __shared__ int s[1024];
    const int t = threadIdx.x;
    const int c = counts[t];
    s[t] = c;
    __syncthreads();
    for (int off = 1; off < 1024; off <<= 1) {
        int v = (t >= off) ? s[t - off] : 0;
        __syncthreads();
        s[t] += v;
        __syncthreads();
    }
    int excl = s[t] - c;
    offsets[t] = excl;
    cursor[t] = excl;
    if (t == 1023) offsets[1024] = s[1023];
}

// Bucket rows by cluster.
__global__ __launch_bounds__(256) void k_scatter(const int* __restrict__ idx,
                                                 int* __restrict__ cursor, int* __restrict__ sorted) {
    int n = blockIdx.x * 256 + threadIdx.x;
    int k = idx[n];
    int p = atomicAdd(&cursor[k], 1);
    sorted[p] = n;
}

// dw gather: one block per cluster, fully coalesced reads, no atomics.
__global__ __launch_bounds__(256) void k_dwg(const float4* __restrict__ flat4,
                                             const int* __restrict__ sorted,
                                             const int* __restrict__ offsets,
                                             float* __restrict__ dw) {
    __shared__ float4 red[256];
    const int k = blockIdx.x;
    const int start = offsets[k], end = offsets[k + 1];
    const int l = threadIdx.x & 63;
    const int g = threadIdx.x >> 6;
    float4 acc = make_float4(0.f, 0.f, 0.f, 0.f);
    for (int r = start + g; r < end; r += 4) {
        int n = sorted[r];
        float4 v = flat4[(size_t)n * 64 + l];
        acc.x += v.x; acc.y += v.y; acc.z += v.z; acc.w += v.w;
    }
    red[threadIdx.x] = acc;
    __syncthreads();
    if (threadIdx.x < 128) {
        float4 o = red[threadIdx.x + 128];
        red[threadIdx.x].x += o.x; red[threadIdx.x].y += o.y;
        red[threadIdx.x].z += o.z; red[threadIdx.x].w += o.w;
    }
    __syncthreads();
    if (threadIdx.x < 64) {
        float4 a = red[threadIdx.x];
        float4 o = red[threadIdx.x + 64];
        a.x += o.x; a.y += o.y; a.z += o.z; a.w += o.w;
        float2* dw2 = (float2*)(dw + (size_t)k * D_);   // dw region is 8B-aligned
        dw2[threadIdx.x * 2]     = make_float2(a.x, a.y);
        dw2[threadIdx.x * 2 + 1] = make_float2(a.z, a.w);
    }
}

// One-hot encodings, float2 stores (region only 8B aligned).
__global__ __launch_bounds__(256) void k_enc(const int* __restrict__ idx, float2* __restrict__ enc) {
    const int base = blockIdx.x * 2048;
    #pragma unroll
    for (int it = 0; it < 8; ++it) {
        int f = base + it * 256 + threadIdx.x;
        int n = f >> 9;
        int k0 = (f & 511) * 2;
        int ki = idx[n];
        float2 v;
        v.x = (k0 == ki) ? 1.0f : 0.0f;
        v.y = (k0 + 1 == ki) ? 1.0f : 0.0f;
        enc[f] = v;
    }
}

// quantized straight-through output (NCHW) + commitment-loss partial sum
__global__ __launch_bounds__(256) void k_quant(
    const float* __restrict__ inp, const float* __restrict__ emb,
    const int* __restrict__ idx, float* __restrict__ outp, float* __restrict__ losssum)
{
    __shared__ float red[256];
    const int tid = threadIdx.x;
    float s = 0.0f;
    const int base = blockIdx.x * 1024;
    #pragma unroll
    for (int it = 0; it < 4; ++it) {
        int g = base + it * 256 + tid;
        int o = g << 2;
        int b = o >> 18;
        int c = (o >> 10) & 255;
        int hw = o & 1023;
        int n = (b << 10) + hw;
        float4 x = ((const float4*)inp)[g];
        int4 ki = *(const int4*)(idx + n);
        float q0 = emb[(size_t)ki.x * D_ + c];
        float q1 = emb[(size_t)ki.y * D_ + c];
        float q2 = emb[(size_t)ki.z * D_ + c];
        float q3 = emb[(size_t)ki.w * D_ + c];
        float d0 = q0 - x.x, d1 = q1 - x.y, d2 = q2 - x.z, d3 = q3 - x.w;
        float4 r = make_float4(x.x + d0, x.y + d1, x.z + d2, x.w + d3);
        ((float4*)outp)[g] = r;
        s += d0 * d0 + d1 * d1 + d2 * d2 + d3 * d3;
    }
    red[tid] = s;
    __syncthreads();
    for (int t = 128; t > 0; t >>= 1) {
        if (tid < t) red[tid] += red[tid + t];
        __syncthreads();
    }
    if (tid == 0) atomicAdd(losssum, red[0]);
}

__global__ __launch_bounds__(1024) void k_cluster(
    const float* __restrict__ ema_cs, const int* __restrict__ counts,
    const float* __restrict__ losssum, float* __restrict__ out_cluster,
    float* __restrict__ out_loss, float* __restrict__ out_ent)
{
    __shared__ float red[1024];
    const int k = threadIdx.x;
    float cnt = (float)counts[k];
    float raw = ema_cs[k] * DECAY_ + OMD_ * cnt;
    red[k] = raw;
    __syncthreads();
    for (int t = 512; t > 0; t >>= 1) {
        if (k < t) red[k] += red[k + t];
        __syncthreads();
    }
    float nsum = red[0];
    __syncthreads();
    float clv = (raw + EPS_) / (nsum + 1024.0f * EPS_) * nsum;
    out_cluster[k] = clv;
    float p = cnt * (1.0f / 65536.0f);
    red[k] = p * logf(p + 1e-10f);
    __syncthreads();
    for (int t = 512; t > 0; t >>= 1) {
        if (k < t) red[k] += red[k + t];
        __syncthreads();
    }
    if (k == 0) {
        out_ent[0] = -red[0];
        out_loss[0] = 0.25f * losssum[0] * (1.0f / 16777216.0f);
    }
}

__global__ __launch_bounds__(256) void k_fin(
    const float* __restrict__ ema_w, const float* __restrict__ cluster,
    float* __restrict__ neww, float* __restrict__ newemb)
{
    int g = blockIdx.x * 256 + threadIdx.x;
    int k = g >> 8;
    float w = ema_w[g] * DECAY_ + OMD_ * neww[g];   // neww currently holds dw
    neww[g] = w;
    newemb[g] = w / cluster[k];
}

extern "C" void kernel_launch(void* const* d_in, const int* in_sizes, int n_in,
                              void* d_out, int out_size, void* d_ws, size_t ws_size,
                              hipStream_t stream)
{
    const float* inp    = (const float*)d_in[0];
    const float* emb    = (const float*)d_in[1];
    const float* ema_cs = (const float*)d_in[2];
    const float* ema_w  = (const float*)d_in[3];

    float* out0        = (float*)d_out;
    float* out_loss    = out0 + OFF_LOSS;
    float* out_ent     = out0 + OFF_ENT;
    float* out_enc     = out0 + OFF_ENC;
    float* out_cluster = out0 + OFF_CLUSTER;
    float* out_neww    = out0 + OFF_NEWW;
    float* out_newemb  = out0 + OFF_NEWEMB;

    // scratch inside encodings region (overwritten by k_enc afterwards)
    float* ws_flat    = out0 + OFF_FLAT;
    int*   ws_sorted  = (int*)(out0 + OFF_SORT);
    int*   ws_offsets = ws_sorted + 65536;
    int*   ws_cursor  = ws_offsets + 1025;

    int*   ws_idx    = (int*)d_ws;
    int*   ws_counts = ws_idx + 65536;
    int*   ws_flagc  = ws_idx + 66560;
    float* ws_loss   = (float*)(ws_idx + 66561);
    int*   ws_flagl  = ws_idx + 66562;
    float* ws_enorm  = (float*)(ws_idx + 132098);

    k_zero   <<<5, 256, 0, stream>>>(ws_counts);
    k_enorm  <<<1024, 64, 0, stream>>>(emb, ws_enorm);
    k_argmin <<<512, 256, 0, stream>>>(inp, emb, ws_enorm, ws_idx, ws_flagc, ws_flagl, ws_flat);
    k_rescan <<<256, 256, 0, stream>>>(inp, emb, ws_flagc, ws_flagl, ws_idx);
    k_hist   <<<64, 256, 0, stream>>>(ws_idx, ws_counts);
    k_scan   <<<1, 1024, 0, stream>>>(ws_counts, ws_offsets, ws_cursor);
    k_scatter<<<256, 256, 0, stream>>>(ws_idx, ws_cursor, ws_sorted);
    k_dwg    <<<1024, 256, 0, stream>>>((const float4*)ws_flat, ws_sorted, ws_offsets, out_neww);
    k_enc    <<<16384, 256, 0, stream>>>(ws_idx, (float2*)out_enc);
    k_quant  <<<4096, 256, 0, stream>>>(inp, emb, ws_idx, out0, ws_loss);
    k_cluster<<<1, 1024, 0, stream>>>(ema_cs, ws_counts, ws_loss, out_cluster, out_loss, out_ent);
    k_fin    <<<1024, 256, 0, stream>>>(ema_w, out_cluster, out_neww, out_newemb);
}

// Round 3
// 1194.435 us; speedup vs baseline: 2.4823x; 1.1147x over previous
//
#include <hip/hip_runtime.h>

// Problem constants
#define B_    64
#define C_    256
#define H_    32
#define W_    32
#define K_    1024
#define D_    256
#define HW_   1024
#define N_    65536
#define NELEM 16777216
#define DECAY_ 0.99f
#define OMD_   0.01f
#define EPS_   1e-5f
#define TAU_   0.05f        // fp64-rescan margin

// d_out float offsets
#define OFF_LOSS    16777216
#define OFF_ENT     16777217
#define OFF_ENC     16777218   // 8B-aligned only
#define OFF_CLUSTER 83886082
#define OFF_NEWW    83887106
#define OFF_NEWEMB  84149250

// Scratch inside the (later overwritten) encodings output region [OFF_ENC, OFF_ENC+67108864):
#define OFF_FLAT    (OFF_ENC + 2)              // 16777220, 16B-aligned; flat fp32 [N][D]
#define OFF_XHI     (OFF_FLAT + 16777216)      // bf16 hi of -2x, [N][D] ushort
#define OFF_XLO     (OFF_XHI + 8388608)
#define OFF_EHI     (OFF_XLO + 8388608)        // bf16 hi of emb, [K][D] ushort
#define OFF_ELO     (OFF_EHI + 131072)
#define OFF_SORT2   (OFF_ELO + 131072)         // sorted[65536] | offsets[1025] | cursor[1024]

typedef __attribute__((ext_vector_type(8))) short short8;
typedef __attribute__((ext_vector_type(4))) float floatx4;

__device__ __forceinline__ unsigned short f2bf(float f) {
    unsigned u = __float_as_uint(f);
    return (unsigned short)((u + 0x7fffu + ((u >> 16) & 1u)) >> 16);
}
__device__ __forceinline__ float bf2f(unsigned short h) {
    return __uint_as_float(((unsigned)h) << 16);
}

__global__ __launch_bounds__(256) void k_zero(int* __restrict__ small_) {
    int g = blockIdx.x * 256 + threadIdx.x;
    if (g < 1026) small_[g] = 0;   // counts[1024] + flagcount + losssum
}

// emb -> bf16 hi/lo + enorm
__global__ __launch_bounds__(64) void k_prep_e(const float* __restrict__ emb,
                                               unsigned short* __restrict__ ehi,
                                               unsigned short* __restrict__ elo,
                                               float* __restrict__ enorm) {
    const int k = blockIdx.x;
    const int t = threadIdx.x;
    float4 v = ((const float4*)(emb + (size_t)k * D_))[t];
    float s = v.x * v.x + v.y * v.y + v.z * v.z + v.w * v.w;
    ushort4 hi, lo;
    {
        float f[4] = {v.x, v.y, v.z, v.w};
        unsigned short h[4], l[4];
        #pragma unroll
        for (int j = 0; j < 4; ++j) {
            h[j] = f2bf(f[j]);
            l[j] = f2bf(f[j] - bf2f(h[j]));
        }
        hi = make_ushort4(h[0], h[1], h[2], h[3]);
        lo = make_ushort4(l[0], l[1], l[2], l[3]);
    }
    *(ushort4*)(ehi + (size_t)k * D_ + t * 4) = hi;
    *(ushort4*)(elo + (size_t)k * D_ + t * 4) = lo;
    #pragma unroll
    for (int off = 32; off > 0; off >>= 1) s += __shfl_down(s, off);
    if (t == 0) enorm[k] = s;
}

// NCHW -> n-major: flat fp32 [n][d], plus bf16 hi/lo split of (-2x).
// Tile: 32 d x 256 n per block.
__global__ __launch_bounds__(256) void k_prep_x(const float* __restrict__ inp,
                                                float* __restrict__ flat,
                                                unsigned short* __restrict__ xhi,
                                                unsigned short* __restrict__ xlo) {
    __shared__ float tile[32][257];
    const int tid = threadIdx.x;
    const int bid = blockIdx.x;            // 2048 blocks: b(64) x hwtile(4) x dtile(8)
    const int dt = bid & 7;
    const int ht = (bid >> 3) & 3;
    const int b = bid >> 5;
    const int d0 = dt * 32;
    const int hw0 = ht * 256;
    const float* src = inp + (size_t)b * (C_ * HW_) + (size_t)d0 * HW_ + hw0;
    #pragma unroll
    for (int i = 0; i < 8; ++i) {
        int idx4 = i * 256 + tid;
        int dl = idx4 >> 6;
        int nl4 = (idx4 & 63) * 4;
        float4 v = *(const float4*)(src + (size_t)dl * HW_ + nl4);
        tile[dl][nl4] = v.x; tile[dl][nl4 + 1] = v.y;
        tile[dl][nl4 + 2] = v.z; tile[dl][nl4 + 3] = v.w;
    }
    __syncthreads();
    const int nbase = b * HW_ + hw0;
    #pragma unroll
    for (int i = 0; i < 8; ++i) {
        int f4 = i * 256 + tid;
        int nl = f4 >> 3;
        int dpos = (f4 & 7) * 4;
        float v0 = tile[dpos][nl], v1 = tile[dpos + 1][nl];
        float v2 = tile[dpos + 2][nl], v3 = tile[dpos + 3][nl];
        size_t o = (size_t)(nbase + nl) * D_ + d0 + dpos;
        *(float4*)(flat + o) = make_float4(v0, v1, v2, v3);
        float f[4] = {-2.0f * v0, -2.0f * v1, -2.0f * v2, -2.0f * v3};
        unsigned short h[4], l[4];
        #pragma unroll
        for (int j = 0; j < 4; ++j) {
            h[j] = f2bf(f[j]);
            l[j] = f2bf(f[j] - bf2f(h[j]));
        }
        *(ushort4*)(xhi + o) = make_ushort4(h[0], h[1], h[2], h[3]);
        *(ushort4*)(xlo + o) = make_ushort4(l[0], l[1], l[2], l[3]);
    }
}

// MFMA bf16x3 distance argmin. Block=256 (4 waves), 128 rows/block, wave=32 rows.
// dist[m][k] = enorm[k] + (-2x_m).e_k  via acc-init=enorm, 3 MFMAs per D-chunk.
__global__ __launch_bounds__(256, 2) void k_argmin(
    const unsigned short* __restrict__ xhi, const unsigned short* __restrict__ xlo,
    const unsigned short* __restrict__ ehi, const unsigned short* __restrict__ elo,
    const float* __restrict__ enorm, int* __restrict__ idx_out,
    int* __restrict__ flagcount, int* __restrict__ flaglist)
{
    const int tid = threadIdx.x;
    const int w = tid >> 6;
    const int lane = tid & 63;
    const int m16 = lane & 15;
    const int quad = lane >> 4;
    const int r0 = blockIdx.x * 128 + w * 32;

    short8 Ahi[2][8], Alo[2][8];
    #pragma unroll
    for (int rt = 0; rt < 2; ++rt) {
        int row = r0 + rt * 16 + m16;
        const unsigned short* ph = xhi + (size_t)row * D_ + quad * 8;
        const unsigned short* pl = xlo + (size_t)row * D_ + quad * 8;
        #pragma unroll
        for (int dc = 0; dc < 8; ++dc) {
            Ahi[rt][dc] = *(const short8*)(ph + dc * 32);
            Alo[rt][dc] = *(const short8*)(pl + dc * 32);
        }
    }

    float b1[8], b2[8];
    int bi[8];
    #pragma unroll
    for (int i = 0; i < 8; ++i) { b1[i] = 3.0e38f; b2[i] = 3.0e38f; bi[i] = 0; }

    for (int ct = 0; ct < K_; ct += 16) {
        const int col = ct + m16;
        const float en = enorm[col];
        floatx4 a0 = {en, en, en, en};
        floatx4 a1 = a0;
        const unsigned short* bh0 = ehi + (size_t)col * D_ + quad * 8;
        const unsigned short* bl0 = elo + (size_t)col * D_ + quad * 8;
        #pragma unroll
        for (int dc = 0; dc < 8; ++dc) {
            short8 bh = *(const short8*)(bh0 + dc * 32);
            short8 bl = *(const short8*)(bl0 + dc * 32);
            a0 = __builtin_amdgcn_mfma_f32_16x16x32_bf16(Ahi[0][dc], bh, a0, 0, 0, 0);
            a1 = __builtin_amdgcn_mfma_f32_16x16x32_bf16(Ahi[1][dc], bh, a1, 0, 0, 0);
            a0 = __builtin_amdgcn_mfma_f32_16x16x32_bf16(Ahi[0][dc], bl, a0, 0, 0, 0);
            a1 = __builtin_amdgcn_mfma_f32_16x16x32_bf16(Ahi[1][dc], bl, a1, 0, 0, 0);
            a0 = __builtin_amdgcn_mfma_f32_16x16x32_bf16(Alo[0][dc], bh, a0, 0, 0, 0);
            a1 = __builtin_amdgcn_mfma_f32_16x16x32_bf16(Alo[1][dc], bh, a1, 0, 0, 0);
        }
        #pragma unroll
        for (int rt = 0; rt < 2; ++rt) {
            #pragma unroll
            for (int reg = 0; reg < 4; ++reg) {
                float v = (rt == 0) ? a0[reg] : a1[reg];
                int s = rt * 4 + reg;
                if (v < b1[s]) { b2[s] = b1[s]; b1[s] = v; bi[s] = col; }
                else if (v < b2[s]) b2[s] = v;
            }
        }
    }

    // reduce across the 16 lanes sharing the same rows (xor 1,2,4,8 stays in 16-group)
    #pragma unroll
    for (int s = 0; s < 8; ++s) {
        float B1 = b1[s], B2 = b2[s];
        int Bi = bi[s];
        #pragma unroll
        for (int mask = 1; mask <= 8; mask <<= 1) {
            float v1 = __shfl_xor(B1, mask);
            float v2 = __shfl_xor(B2, mask);
            int i1 = __shfl_xor(Bi, mask);
            if (v1 < B1 || (v1 == B1 && i1 < Bi)) {
                B2 = fminf(fminf(B1, B2), v2);
                B1 = v1; Bi = i1;
            } else {
                B2 = fminf(B2, fminf(v1, v2));
            }
        }
        if (m16 == 0) {
            int row = r0 + (s >> 2) * 16 + quad * 4 + (s & 3);
            idx_out[row] = Bi;
            if (B2 - B1 < TAU_) {
                int p = atomicAdd(flagcount, 1);
                flaglist[p] = row;
            }
        }
    }
}

// Exact fp64 rescan of flagged (near-tie) rows.
__global__ __launch_bounds__(256) void k_rescan(
    const float* __restrict__ inp, const float* __restrict__ emb,
    const int* __restrict__ flagcount, const int* __restrict__ flaglist,
    int* __restrict__ idx_out)
{
    __shared__ double xd[256];
    __shared__ double sv[256];
    __shared__ int si[256];
    const int tid = threadIdx.x;
    const int nflag = *flagcount;
    for (int f = blockIdx.x; f < nflag; f += gridDim.x) {
        int n = flaglist[f];
        int b = n >> 10, nn = n & 1023;
        xd[tid] = (double)inp[(size_t)b * (C_ * HW_) + (size_t)tid * HW_ + nn];
        __syncthreads();
        double bv = 1e300; int bi = 0;
        for (int k = tid; k < K_; k += 256) {
            const float* ep = emb + (size_t)k * D_;
            double dot = 0.0, en = 0.0;
            for (int d = 0; d < D_; ++d) {
                double e = (double)ep[d];
                dot = fma(xd[d], e, dot);
                en  = fma(e, e, en);
            }
            double v = en - 2.0 * dot;
            if (v < bv) { bv = v; bi = k; }
        }
        sv[tid] = bv; si[tid] = bi;
        __syncthreads();
        for (int s = 128; s > 0; s >>= 1) {
            if (tid < s) {
                if (sv[tid + s] < sv[tid] || (sv[tid + s] == sv[tid] && si[tid + s] < si[tid])) {
                    sv[tid] = sv[tid + s]; si[tid] = si[tid + s];
                }
            }
            __syncthreads();
        }
        if (tid == 0) idx_out[n] = si[0];
        __syncthreads();
    }
}

__global__ __launch_bounds__(256) void k_hist(const int* __restrict__ idx, int* __restrict__ counts) {
    __shared__ int h[1024];
    const int tid = threadIdx.x;
    #pragma unroll
    for (int j = 0; j < 4; ++j) h[tid + j * 256] = 0;
    __syncthreads();
    #pragma unroll
    for (int j = 0; j < 4; ++j) {
        int n = blockIdx.x * 1024 + j * 256 + tid;
        atomicAdd(&h[idx[n]], 1);
    }
    __syncthreads();
    #pragma unroll
    for (int j = 0; j < 4; ++j) {
        int v = h[tid + j * 256];
        if (v) atomicAdd(&counts[tid + j * 256], v);
    }
}

__global__ __launch_bounds__(1024) void k_scan(const int* __restrict__ counts,
                                               int* __restrict__ offsets, int* __restrict__ cursor) {
    __shared__ int s[1024];
    const int t = threadIdx.x;
    const int c = counts[t];
    s[t] = c;
    __syncthreads();
    for (int off = 1; off < 1024; off <<= 1) {
        int v = (t >= off) ? s[t - off] : 0;
        __syncthreads();
        s[t] += v;
        __syncthreads();
    }
    int excl = s[t] - c;
    offsets[t] = excl;
    cursor[t] = excl;
    if (t == 1023) offsets[1024] = s[1023];
}

__global__ __launch_bounds__(256) void k_scatter(const int* __restrict__ idx,
                                                 int* __restrict__ cursor, int* __restrict__ sorted) {
    int n = blockIdx.x * 256 + threadIdx.x;
    int k = idx[n];
    int p = atomicAdd(&cursor[k], 1);
    sorted[p] = n;
}

__global__ __launch_bounds__(256) void k_dwg(const float4* __restrict__ flat4,
                                             const int* __restrict__ sorted,
                                             const int* __restrict__ offsets,
                                             float* __restrict__ dw) {
    __shared__ float4 red[256];
    const int k = blockIdx.x;
    const int start = offsets[k], end = offsets[k + 1];
    const int l = threadIdx.x & 63;
    const int g = threadIdx.x >> 6;
    float4 acc = make_float4(0.f, 0.f, 0.f, 0.f);
    for (int r = start + g; r < end; r += 4) {
        int n = sorted[r];
        float4 v = flat4[(size_t)n * 64 + l];
        acc.x += v.x; acc.y += v.y; acc.z += v.z; acc.w += v.w;
    }
    red[threadIdx.x] = acc;
    __syncthreads();
    if (threadIdx.x < 128) {
        float4 o = red[threadIdx.x + 128];
        red[threadIdx.x].x += o.x; red[threadIdx.x].y += o.y;
        red[threadIdx.x].z += o.z; red[threadIdx.x].w += o.w;
    }
    __syncthreads();
    if (threadIdx.x < 64) {
        float4 a = red[threadIdx.x];
        float4 o = red[threadIdx.x + 64];
        a.x += o.x; a.y += o.y; a.z += o.z; a.w += o.w;
        float2* dw2 = (float2*)(dw + (size_t)k * D_);
        dw2[threadIdx.x * 2]     = make_float2(a.x, a.y);
        dw2[threadIdx.x * 2 + 1] = make_float2(a.z, a.w);
    }
}

__global__ __launch_bounds__(256) void k_enc(const int* __restrict__ idx, float2* __restrict__ enc) {
    const int base = blockIdx.x * 2048;
    #pragma unroll
    for (int it = 0; it < 8; ++it) {
        int f = base + it * 256 + threadIdx.x;
        int n = f >> 9;
        int k0 = (f & 511) * 2;
        int ki = idx[n];
        float2 v;
        v.x = (k0 == ki) ? 1.0f : 0.0f;
        v.y = (k0 + 1 == ki) ? 1.0f : 0.0f;
        enc[f] = v;
    }
}

__global__ __launch_bounds__(256) void k_quant(
    const float* __restrict__ inp, const float* __restrict__ emb,
    const int* __restrict__ idx, float* __restrict__ outp, float* __restrict__ losssum)
{
    __shared__ float red[256];
    const int tid = threadIdx.x;
    float s = 0.0f;
    const int base = blockIdx.x * 1024;
    #pragma unroll
    for (int it = 0; it < 4; ++it) {
        int g = base + it * 256 + tid;
        int o = g << 2;
        int b = o >> 18;
        int c = (o >> 10) & 255;
        int hw = o & 1023;
        int n = (b << 10) + hw;
        float4 x = ((const float4*)inp)[g];
        int4 ki = *(const int4*)(idx + n);
        float q0 = emb[(size_t)ki.x * D_ + c];
        float q1 = emb[(size_t)ki.y * D_ + c];
        float q2 = emb[(size_t)ki.z * D_ + c];
        float q3 = emb[(size_t)ki.w * D_ + c];
        float d0 = q0 - x.x, d1 = q1 - x.y, d2 = q2 - x.z, d3 = q3 - x.w;
        ((float4*)outp)[g] = make_float4(x.x + d0, x.y + d1, x.z + d2, x.w + d3);
        s += d0 * d0 + d1 * d1 + d2 * d2 + d3 * d3;
    }
    red[tid] = s;
    __syncthreads();
    for (int t = 128; t > 0; t >>= 1) {
        if (tid < t) red[tid] += red[tid + t];
        __syncthreads();
    }
    if (tid == 0) atomicAdd(losssum, red[0]);
}

__global__ __launch_bounds__(1024) void k_cluster(
    const float* __restrict__ ema_cs, const int* __restrict__ counts,
    const float* __restrict__ losssum, float* __restrict__ out_cluster,
    float* __restrict__ out_loss, float* __restrict__ out_ent)
{
    __shared__ float red[1024];
    const int k = threadIdx.x;
    float cnt = (float)counts[k];
    float raw = ema_cs[k] * DECAY_ + OMD_ * cnt;
    red[k] = raw;
    __syncthreads();
    for (int t = 512; t > 0; t >>= 1) {
        if (k < t) red[k] += red[k + t];
        __syncthreads();
    }
    float nsum = red[0];
    __syncthreads();
    float clv = (raw + EPS_) / (nsum + 1024.0f * EPS_) * nsum;
    out_cluster[k] = clv;
    float p = cnt * (1.0f / 65536.0f);
    red[k] = p * logf(p + 1e-10f);
    __syncthreads();
    for (int t = 512; t > 0; t >>= 1) {
        if (k < t) red[k] += red[k + t];
        __syncthreads();
    }
    if (k == 0) {
        out_ent[0] = -red[0];
        out_loss[0] = 0.25f * losssum[0] * (1.0f / 16777216.0f);
    }
}

__global__ __launch_bounds__(256) void k_fin(
    const float* __restrict__ ema_w, const float* __restrict__ cluster,
    float* __restrict__ neww, float* __restrict__ newemb)
{
    int g = blockIdx.x * 256 + threadIdx.x;
    int k = g >> 8;
    float w = ema_w[g] * DECAY_ + OMD_ * neww[g];   // neww currently holds dw
    neww[g] = w;
    newemb[g] = w / cluster[k];
}

extern "C" void kernel_launch(void* const* d_in, const int* in_sizes, int n_in,
                              void* d_out, int out_size, void* d_ws, size_t ws_size,
                              hipStream_t stream)
{
    const float* inp    = (const float*)d_in[0];
    const float* emb    = (const float*)d_in[1];
    const float* ema_cs = (const float*)d_in[2];
    const float* ema_w  = (const float*)d_in[3];

    float* out0        = (float*)d_out;
    float* out_loss    = out0 + OFF_LOSS;
    float* out_ent     = out0 + OFF_ENT;
    float* out_enc     = out0 + OFF_ENC;
    float* out_cluster = out0 + OFF_CLUSTER;
    float* out_neww    = out0 + OFF_NEWW;
    float* out_newemb  = out0 + OFF_NEWEMB;

    float*          ws_flat = out0 + OFF_FLAT;
    unsigned short* ws_xhi  = (unsigned short*)(out0 + OFF_XHI);
    unsigned short* ws_xlo  = (unsigned short*)(out0 + OFF_XLO);
    unsigned short* ws_ehi  = (unsigned short*)(out0 + OFF_EHI);
    unsigned short* ws_elo  = (unsigned short*)(out0 + OFF_ELO);
    int*   ws_sorted  = (int*)(out0 + OFF_SORT2);
    int*   ws_offsets = ws_sorted + 65536;
    int*   ws_cursor  = ws_offsets + 1025;

    int*   ws_idx    = (int*)d_ws;
    int*   ws_counts = ws_idx + 65536;
    int*   ws_flagc  = ws_idx + 66560;
    float* ws_loss   = (float*)(ws_idx + 66561);
    int*   ws_flagl  = ws_idx + 66562;
    float* ws_enorm  = (float*)(ws_idx + 132098);

    k_zero   <<<5, 256, 0, stream>>>(ws_counts);
    k_prep_e <<<1024, 64, 0, stream>>>(emb, ws_ehi, ws_elo, ws_enorm);
    k_prep_x <<<2048, 256, 0, stream>>>(inp, ws_flat, ws_xhi, ws_xlo);
    k_argmin <<<512, 256, 0, stream>>>(ws_xhi, ws_xlo, ws_ehi, ws_elo, ws_enorm,
                                       ws_idx, ws_flagc, ws_flagl);
    k_rescan <<<256, 256, 0, stream>>>(inp, emb, ws_flagc, ws_flagl, ws_idx);
    k_hist   <<<64, 256, 0, stream>>>(ws_idx, ws_counts);
    k_scan   <<<1, 1024, 0, stream>>>(ws_counts, ws_offsets, ws_cursor);
    k_scatter<<<256, 256, 0, stream>>>(ws_idx, ws_cursor, ws_sorted);
    k_dwg    <<<1024, 256, 0, stream>>>((const float4*)ws_flat, ws_sorted, ws_offsets, out_neww);
    k_enc    <<<16384, 256, 0, stream>>>(ws_idx, (float2*)out_enc);
    k_quant  <<<4096, 256, 0, stream>>>(inp, emb, ws_idx, out0, ws_loss);
    k_cluster<<<1, 1024, 0, stream>>>(ema_cs, ws_counts, ws_loss, out_cluster, out_loss, out_ent);
    k_fin    <<<1024, 256, 0, stream>>>(ema_w, out_cluster, out_neww, out_newemb);
}

// Round 4
// 898.028 us; speedup vs baseline: 3.3017x; 1.3301x over previous
//
#include <hip/hip_runtime.h>

// Problem constants
#define B_    64
#define C_    256
#define H_    32
#define W_    32
#define K_    1024
#define D_    256
#define HW_   1024
#define N_    65536
#define NELEM 16777216
#define DECAY_ 0.99f
#define OMD_   0.01f
#define EPS_   1e-5f
#define TAU_   0.05f        // fp64-rescan margin

// d_out float offsets
#define OFF_LOSS    16777216
#define OFF_ENT     16777217
#define OFF_ENC     16777218   // 8B-aligned only
#define OFF_CLUSTER 83886082
#define OFF_NEWW    83887106
#define OFF_NEWEMB  84149250

// Scratch inside the (later overwritten) encodings output region [OFF_ENC, OFF_ENC+67108864):
#define OFF_FLAT    (OFF_ENC + 2)              // 16777220, 16B-aligned; flat fp32 [N][D]
#define OFF_XHI     (OFF_FLAT + 16777216)      // bf16 hi of -2x, [N][D] ushort
#define OFF_XLO     (OFF_XHI + 8388608)
#define OFF_EHI     (OFF_XLO + 8388608)        // bf16 hi of emb, [K][D] ushort
#define OFF_ELO     (OFF_EHI + 131072)
#define OFF_SORT2   (OFF_ELO + 131072)         // sorted[65536] | offsets[1025] | cursor[1024]

typedef __attribute__((ext_vector_type(8))) short short8;
typedef __attribute__((ext_vector_type(4))) float floatx4;

__device__ __forceinline__ unsigned short f2bf(float f) {
    unsigned u = __float_as_uint(f);
    return (unsigned short)((u + 0x7fffu + ((u >> 16) & 1u)) >> 16);
}
__device__ __forceinline__ float bf2f(unsigned short h) {
    return __uint_as_float(((unsigned)h) << 16);
}

__global__ __launch_bounds__(256) void k_zero(float* __restrict__ dw, int* __restrict__ small_) {
    int g = blockIdx.x * 256 + threadIdx.x;
    dw[g] = 0.0f;                  // grid 1024*256 == 262144 == K*D exactly
    if (g < 1026) small_[g] = 0;   // counts[1024] + flagcount + losssum
}

// emb -> bf16 hi/lo + enorm
__global__ __launch_bounds__(64) void k_prep_e(const float* __restrict__ emb,
                                               unsigned short* __restrict__ ehi,
                                               unsigned short* __restrict__ elo,
                                               float* __restrict__ enorm) {
    const int k = blockIdx.x;
    const int t = threadIdx.x;
    float4 v = ((const float4*)(emb + (size_t)k * D_))[t];
    float s = v.x * v.x + v.y * v.y + v.z * v.z + v.w * v.w;
    ushort4 hi, lo;
    {
        float f[4] = {v.x, v.y, v.z, v.w};
        unsigned short h[4], l[4];
        #pragma unroll
        for (int j = 0; j < 4; ++j) {
            h[j] = f2bf(f[j]);
            l[j] = f2bf(f[j] - bf2f(h[j]));
        }
        hi = make_ushort4(h[0], h[1], h[2], h[3]);
        lo = make_ushort4(l[0], l[1], l[2], l[3]);
    }
    *(ushort4*)(ehi + (size_t)k * D_ + t * 4) = hi;
    *(ushort4*)(elo + (size_t)k * D_ + t * 4) = lo;
    #pragma unroll
    for (int off = 32; off > 0; off >>= 1) s += __shfl_down(s, off);
    if (t == 0) enorm[k] = s;
}

// NCHW -> n-major: flat fp32 [n][d], plus bf16 hi/lo split of (-2x).
__global__ __launch_bounds__(256) void k_prep_x(const float* __restrict__ inp,
                                                float* __restrict__ flat,
                                                unsigned short* __restrict__ xhi,
                                                unsigned short* __restrict__ xlo) {
    __shared__ float tile[32][257];
    const int tid = threadIdx.x;
    const int bid = blockIdx.x;            // 2048 blocks: b(64) x hwtile(4) x dtile(8)
    const int dt = bid & 7;
    const int ht = (bid >> 3) & 3;
    const int b = bid >> 5;
    const int d0 = dt * 32;
    const int hw0 = ht * 256;
    const float* src = inp + (size_t)b * (C_ * HW_) + (size_t)d0 * HW_ + hw0;
    #pragma unroll
    for (int i = 0; i < 8; ++i) {
        int idx4 = i * 256 + tid;
        int dl = idx4 >> 6;
        int nl4 = (idx4 & 63) * 4;
        float4 v = *(const float4*)(src + (size_t)dl * HW_ + nl4);
        tile[dl][nl4] = v.x; tile[dl][nl4 + 1] = v.y;
        tile[dl][nl4 + 2] = v.z; tile[dl][nl4 + 3] = v.w;
    }
    __syncthreads();
    const int nbase = b * HW_ + hw0;
    #pragma unroll
    for (int i = 0; i < 8; ++i) {
        int f4 = i * 256 + tid;
        int nl = f4 >> 3;
        int dpos = (f4 & 7) * 4;
        float v0 = tile[dpos][nl], v1 = tile[dpos + 1][nl];
        float v2 = tile[dpos + 2][nl], v3 = tile[dpos + 3][nl];
        size_t o = (size_t)(nbase + nl) * D_ + d0 + dpos;
        *(float4*)(flat + o) = make_float4(v0, v1, v2, v3);
        float f[4] = {-2.0f * v0, -2.0f * v1, -2.0f * v2, -2.0f * v3};
        unsigned short h[4], l[4];
        #pragma unroll
        for (int j = 0; j < 4; ++j) {
            h[j] = f2bf(f[j]);
            l[j] = f2bf(f[j] - bf2f(h[j]));
        }
        *(ushort4*)(xhi + o) = make_ushort4(h[0], h[1], h[2], h[3]);
        *(ushort4*)(xlo + o) = make_ushort4(l[0], l[1], l[2], l[3]);
    }
}

// MFMA bf16x3 distance argmin.
__global__ __launch_bounds__(256, 2) void k_argmin(
    const unsigned short* __restrict__ xhi, const unsigned short* __restrict__ xlo,
    const unsigned short* __restrict__ ehi, const unsigned short* __restrict__ elo,
    const float* __restrict__ enorm, int* __restrict__ idx_out,
    int* __restrict__ flagcount, int* __restrict__ flaglist)
{
    const int tid = threadIdx.x;
    const int w = tid >> 6;
    const int lane = tid & 63;
    const int m16 = lane & 15;
    const int quad = lane >> 4;
    const int r0 = blockIdx.x * 128 + w * 32;

    short8 Ahi[2][8], Alo[2][8];
    #pragma unroll
    for (int rt = 0; rt < 2; ++rt) {
        int row = r0 + rt * 16 + m16;
        const unsigned short* ph = xhi + (size_t)row * D_ + quad * 8;
        const unsigned short* pl = xlo + (size_t)row * D_ + quad * 8;
        #pragma unroll
        for (int dc = 0; dc < 8; ++dc) {
            Ahi[rt][dc] = *(const short8*)(ph + dc * 32);
            Alo[rt][dc] = *(const short8*)(pl + dc * 32);
        }
    }

    float b1[8], b2[8];
    int bi[8];
    #pragma unroll
    for (int i = 0; i < 8; ++i) { b1[i] = 3.0e38f; b2[i] = 3.0e38f; bi[i] = 0; }

    for (int ct = 0; ct < K_; ct += 16) {
        const int col = ct + m16;
        const float en = enorm[col];
        floatx4 a0 = {en, en, en, en};
        floatx4 a1 = a0;
        const unsigned short* bh0 = ehi + (size_t)col * D_ + quad * 8;
        const unsigned short* bl0 = elo + (size_t)col * D_ + quad * 8;
        #pragma unroll
        for (int dc = 0; dc < 8; ++dc) {
            short8 bh = *(const short8*)(bh0 + dc * 32);
            short8 bl = *(const short8*)(bl0 + dc * 32);
            a0 = __builtin_amdgcn_mfma_f32_16x16x32_bf16(Ahi[0][dc], bh, a0, 0, 0, 0);
            a1 = __builtin_amdgcn_mfma_f32_16x16x32_bf16(Ahi[1][dc], bh, a1, 0, 0, 0);
            a0 = __builtin_amdgcn_mfma_f32_16x16x32_bf16(Ahi[0][dc], bl, a0, 0, 0, 0);
            a1 = __builtin_amdgcn_mfma_f32_16x16x32_bf16(Ahi[1][dc], bl, a1, 0, 0, 0);
            a0 = __builtin_amdgcn_mfma_f32_16x16x32_bf16(Alo[0][dc], bh, a0, 0, 0, 0);
            a1 = __builtin_amdgcn_mfma_f32_16x16x32_bf16(Alo[1][dc], bh, a1, 0, 0, 0);
        }
        #pragma unroll
        for (int rt = 0; rt < 2; ++rt) {
            #pragma unroll
            for (int reg = 0; reg < 4; ++reg) {
                float v = (rt == 0) ? a0[reg] : a1[reg];
                int s = rt * 4 + reg;
                if (v < b1[s]) { b2[s] = b1[s]; b1[s] = v; bi[s] = col; }
                else if (v < b2[s]) b2[s] = v;
            }
        }
    }

    #pragma unroll
    for (int s = 0; s < 8; ++s) {
        float B1 = b1[s], B2 = b2[s];
        int Bi = bi[s];
        #pragma unroll
        for (int mask = 1; mask <= 8; mask <<= 1) {
            float v1 = __shfl_xor(B1, mask);
            float v2 = __shfl_xor(B2, mask);
            int i1 = __shfl_xor(Bi, mask);
            if (v1 < B1 || (v1 == B1 && i1 < Bi)) {
                B2 = fminf(fminf(B1, B2), v2);
                B1 = v1; Bi = i1;
            } else {
                B2 = fminf(B2, fminf(v1, v2));
            }
        }
        if (m16 == 0) {
            int row = r0 + (s >> 2) * 16 + quad * 4 + (s & 3);
            idx_out[row] = Bi;
            if (B2 - B1 < TAU_) {
                int p = atomicAdd(flagcount, 1);
                flaglist[p] = row;
            }
        }
    }
}

// Exact fp64 rescan of flagged (near-tie) rows.
__global__ __launch_bounds__(256) void k_rescan(
    const float* __restrict__ inp, const float* __restrict__ emb,
    const int* __restrict__ flagcount, const int* __restrict__ flaglist,
    int* __restrict__ idx_out)
{
    __shared__ double xd[256];
    __shared__ double sv[256];
    __shared__ int si[256];
    const int tid = threadIdx.x;
    const int nflag = *flagcount;
    for (int f = blockIdx.x; f < nflag; f += gridDim.x) {
        int n = flaglist[f];
        int b = n >> 10, nn = n & 1023;
        xd[tid] = (double)inp[(size_t)b * (C_ * HW_) + (size_t)tid * HW_ + nn];
        __syncthreads();
        double bv = 1e300; int bi = 0;
        for (int k = tid; k < K_; k += 256) {
            const float* ep = emb + (size_t)k * D_;
            double dot = 0.0, en = 0.0;
            for (int d = 0; d < D_; ++d) {
                double e = (double)ep[d];
                dot = fma(xd[d], e, dot);
                en  = fma(e, e, en);
            }
            double v = en - 2.0 * dot;
            if (v < bv) { bv = v; bi = k; }
        }
        sv[tid] = bv; si[tid] = bi;
        __syncthreads();
        for (int s = 128; s > 0; s >>= 1) {
            if (tid < s) {
                if (sv[tid + s] < sv[tid] || (sv[tid + s] == sv[tid] && si[tid + s] < si[tid])) {
                    sv[tid] = sv[tid + s]; si[tid] = si[tid + s];
                }
            }
            __syncthreads();
        }
        if (tid == 0) idx_out[n] = si[0];
        __syncthreads();
    }
}

__global__ __launch_bounds__(256) void k_hist(const int* __restrict__ idx, int* __restrict__ counts) {
    __shared__ int h[1024];
    const int tid = threadIdx.x;
    #pragma unroll
    for (int j = 0; j < 4; ++j) h[tid + j * 256] = 0;
    __syncthreads();
    #pragma unroll
    for (int j = 0; j < 4; ++j) {
        int n = blockIdx.x * 1024 + j * 256 + tid;
        atomicAdd(&h[idx[n]], 1);
    }
    __syncthreads();
    #pragma unroll
    for (int j = 0; j < 4; ++j) {
        int v = h[tid + j * 256];
        if (v) atomicAdd(&counts[tid + j * 256], v);
    }
}

__global__ __launch_bounds__(1024) void k_scan(const int* __restrict__ counts,
                                               int* __restrict__ offsets, int* __restrict__ cursor) {
    __shared__ int s[1024];
    const int t = threadIdx.x;
    const int c = counts[t];
    s[t] = c;
    __syncthreads();
    for (int off = 1; off < 1024; off <<= 1) {
        int v = (t >= off) ? s[t - off] : 0;
        __syncthreads();
        s[t] += v;
        __syncthreads();
    }
    int excl = s[t] - c;
    offsets[t] = excl;
    cursor[t] = excl;
    if (t == 1023) offsets[1024] = s[1023];
}

// Block-aggregated scatter: LDS histogram -> 1 global atomic per (block,cluster) -> LDS-cursor scatter.
__global__ __launch_bounds__(256) void k_scatter(const int* __restrict__ idx,
                                                 int* __restrict__ cursor, int* __restrict__ sorted) {
    __shared__ int hc[1024];
    __shared__ int hb[1024];
    const int tid = threadIdx.x;
    const int base = blockIdx.x * 1024;
    #pragma unroll
    for (int j = 0; j < 4; ++j) hc[tid + j * 256] = 0;
    __syncthreads();
    int myk[4], myn[4];
    #pragma unroll
    for (int j = 0; j < 4; ++j) {
        int n = base + j * 256 + tid;
        myn[j] = n;
        myk[j] = idx[n];
        atomicAdd(&hc[myk[j]], 1);
    }
    __syncthreads();
    #pragma unroll
    for (int j = 0; j < 4; ++j) {
        int kk = tid + j * 256;
        int c = hc[kk];
        hb[kk] = c ? atomicAdd(&cursor[kk], c) : 0;
    }
    __syncthreads();
    #pragma unroll
    for (int j = 0; j < 4; ++j) hc[tid + j * 256] = 0;
    __syncthreads();
    #pragma unroll
    for (int j = 0; j < 4; ++j) {
        int p = hb[myk[j]] + atomicAdd(&hc[myk[j]], 1);
        sorted[p] = myn[j];
    }
}

// Balanced segmented dw reduction: each wave owns 64 consecutive sorted rows.
// Runs fully inside the wave-chunk -> direct store; boundary runs -> atomicAdd (dw pre-zeroed).
__global__ __launch_bounds__(256) void k_dwg(const float4* __restrict__ flat4,
                                             const int* __restrict__ sorted,
                                             const int* __restrict__ idx,
                                             const int* __restrict__ offsets,
                                             float* __restrict__ dw) {
    const int lane = threadIdx.x & 63;
    const int wid = threadIdx.x >> 6;
    const int wbase = (blockIdx.x * 4 + wid) * 64;

    int myn = sorted[wbase + lane];
    int myk = idx[myn];

    float4 acc = make_float4(0.f, 0.f, 0.f, 0.f);
    int cur = __shfl(myk, 0);

    #pragma unroll 8
    for (int i = 0; i < 64; ++i) {
        int n = __shfl(myn, i);
        int k = __shfl(myk, i);
        if (k != cur) {
            // flush run for cluster `cur`
            bool full = (offsets[cur] >= wbase) && (offsets[cur + 1] <= wbase + 64);
            float* dwk = dw + (size_t)cur * D_ + lane * 4;
            if (full) {
                ((float2*)dwk)[0] = make_float2(acc.x, acc.y);
                ((float2*)dwk)[1] = make_float2(acc.z, acc.w);
            } else {
                atomicAdd(dwk + 0, acc.x);
                atomicAdd(dwk + 1, acc.y);
                atomicAdd(dwk + 2, acc.z);
                atomicAdd(dwk + 3, acc.w);
            }
            acc = make_float4(0.f, 0.f, 0.f, 0.f);
            cur = k;
        }
        float4 v = flat4[(size_t)n * 64 + lane];
        acc.x += v.x; acc.y += v.y; acc.z += v.z; acc.w += v.w;
    }
    {
        bool full = (offsets[cur] >= wbase) && (offsets[cur + 1] <= wbase + 64);
        float* dwk = dw + (size_t)cur * D_ + lane * 4;
        if (full) {
            ((float2*)dwk)[0] = make_float2(acc.x, acc.y);
            ((float2*)dwk)[1] = make_float2(acc.z, acc.w);
        } else {
            atomicAdd(dwk + 0, acc.x);
            atomicAdd(dwk + 1, acc.y);
            atomicAdd(dwk + 2, acc.z);
            atomicAdd(dwk + 3, acc.w);
        }
    }
}

__global__ __launch_bounds__(256) void k_enc(const int* __restrict__ idx, float2* __restrict__ enc) {
    const int base = blockIdx.x * 2048;
    #pragma unroll
    for (int it = 0; it < 8; ++it) {
        int f = base + it * 256 + threadIdx.x;
        int n = f >> 9;
        int k0 = (f & 511) * 2;
        int ki = idx[n];
        float2 v;
        v.x = (k0 == ki) ? 1.0f : 0.0f;
        v.y = (k0 + 1 == ki) ? 1.0f : 0.0f;
        enc[f] = v;
    }
}

__global__ __launch_bounds__(256) void k_quant(
    const float* __restrict__ inp, const float* __restrict__ emb,
    const int* __restrict__ idx, float* __restrict__ outp, float* __restrict__ losssum)
{
    __shared__ float red[256];
    const int tid = threadIdx.x;
    float s = 0.0f;
    const int base = blockIdx.x * 1024;
    #pragma unroll
    for (int it = 0; it < 4; ++it) {
        int g = base + it * 256 + tid;
        int o = g << 2;
        int b = o >> 18;
        int c = (o >> 10) & 255;
        int hw = o & 1023;
        int n = (b << 10) + hw;
        float4 x = ((const float4*)inp)[g];
        int4 ki = *(const int4*)(idx + n);
        float q0 = emb[(size_t)ki.x * D_ + c];
        float q1 = emb[(size_t)ki.y * D_ + c];
        float q2 = emb[(size_t)ki.z * D_ + c];
        float q3 = emb[(size_t)ki.w * D_ + c];
        float d0 = q0 - x.x, d1 = q1 - x.y, d2 = q2 - x.z, d3 = q3 - x.w;
        ((float4*)outp)[g] = make_float4(x.x + d0, x.y + d1, x.z + d2, x.w + d3);
        s += d0 * d0 + d1 * d1 + d2 * d2 + d3 * d3;
    }
    red[tid] = s;
    __syncthreads();
    for (int t = 128; t > 0; t >>= 1) {
        if (tid < t) red[tid] += red[tid + t];
        __syncthreads();
    }
    if (tid == 0) atomicAdd(losssum, red[0]);
}

__global__ __launch_bounds__(1024) void k_cluster(
    const float* __restrict__ ema_cs, const int* __restrict__ counts,
    const float* __restrict__ losssum, float* __restrict__ out_cluster,
    float* __restrict__ out_loss, float* __restrict__ out_ent)
{
    __shared__ float red[1024];
    const int k = threadIdx.x;
    float cnt = (float)counts[k];
    float raw = ema_cs[k] * DECAY_ + OMD_ * cnt;
    red[k] = raw;
    __syncthreads();
    for (int t = 512; t > 0; t >>= 1) {
        if (k < t) red[k] += red[k + t];
        __syncthreads();
    }
    float nsum = red[0];
    __syncthreads();
    float clv = (raw + EPS_) / (nsum + 1024.0f * EPS_) * nsum;
    out_cluster[k] = clv;
    float p = cnt * (1.0f / 65536.0f);
    red[k] = p * logf(p + 1e-10f);
    __syncthreads();
    for (int t = 512; t > 0; t >>= 1) {
        if (k < t) red[k] += red[k + t];
        __syncthreads();
    }
    if (k == 0) {
        out_ent[0] = -red[0];
        out_loss[0] = 0.25f * losssum[0] * (1.0f / 16777216.0f);
    }
}

__global__ __launch_bounds__(256) void k_fin(
    const float* __restrict__ ema_w, const float* __restrict__ cluster,
    float* __restrict__ neww, float* __restrict__ newemb)
{
    int g = blockIdx.x * 256 + threadIdx.x;
    int k = g >> 8;
    float w = ema_w[g] * DECAY_ + OMD_ * neww[g];   // neww currently holds dw
    neww[g] = w;
    newemb[g] = w / cluster[k];
}

extern "C" void kernel_launch(void* const* d_in, const int* in_sizes, int n_in,
                              void* d_out, int out_size, void* d_ws, size_t ws_size,
                              hipStream_t stream)
{
    const float* inp    = (const float*)d_in[0];
    const float* emb    = (const float*)d_in[1];
    const float* ema_cs = (const float*)d_in[2];
    const float* ema_w  = (const float*)d_in[3];

    float* out0        = (float*)d_out;
    float* out_loss    = out0 + OFF_LOSS;
    float* out_ent     = out0 + OFF_ENT;
    float* out_enc     = out0 + OFF_ENC;
    float* out_cluster = out0 + OFF_CLUSTER;
    float* out_neww    = out0 + OFF_NEWW;
    float* out_newemb  = out0 + OFF_NEWEMB;

    float*          ws_flat = out0 + OFF_FLAT;
    unsigned short* ws_xhi  = (unsigned short*)(out0 + OFF_XHI);
    unsigned short* ws_xlo  = (unsigned short*)(out0 + OFF_XLO);
    unsigned short* ws_ehi  = (unsigned short*)(out0 + OFF_EHI);
    unsigned short* ws_elo  = (unsigned short*)(out0 + OFF_ELO);
    int*   ws_sorted  = (int*)(out0 + OFF_SORT2);
    int*   ws_offsets = ws_sorted + 65536;
    int*   ws_cursor  = ws_offsets + 1025;

    int*   ws_idx    = (int*)d_ws;
    int*   ws_counts = ws_idx + 65536;
    int*   ws_flagc  = ws_idx + 66560;
    float* ws_loss   = (float*)(ws_idx + 66561);
    int*   ws_flagl  = ws_idx + 66562;
    float* ws_enorm  = (float*)(ws_idx + 132098);

    k_zero   <<<1024, 256, 0, stream>>>(out_neww, ws_counts);
    k_prep_e <<<1024, 64, 0, stream>>>(emb, ws_ehi, ws_elo, ws_enorm);
    k_prep_x <<<2048, 256, 0, stream>>>(inp, ws_flat, ws_xhi, ws_xlo);
    k_argmin <<<512, 256, 0, stream>>>(ws_xhi, ws_xlo, ws_ehi, ws_elo, ws_enorm,
                                       ws_idx, ws_flagc, ws_flagl);
    k_rescan <<<256, 256, 0, stream>>>(inp, emb, ws_flagc, ws_flagl, ws_idx);
    k_hist   <<<64, 256, 0, stream>>>(ws_idx, ws_counts);
    k_scan   <<<1, 1024, 0, stream>>>(ws_counts, ws_offsets, ws_cursor);
    k_scatter<<<64, 256, 0, stream>>>(ws_idx, ws_cursor, ws_sorted);
    k_dwg    <<<256, 256, 0, stream>>>((const float4*)ws_flat, ws_sorted, ws_idx, ws_offsets, out_neww);
    k_enc    <<<16384, 256, 0, stream>>>(ws_idx, (float2*)out_enc);
    k_quant  <<<4096, 256, 0, stream>>>(inp, emb, ws_idx, out0, ws_loss);
    k_cluster<<<1, 1024, 0, stream>>>(ema_cs, ws_counts, ws_loss, out_cluster, out_loss, out_ent);
    k_fin    <<<1024, 256, 0, stream>>>(ema_w, out_cluster, out_neww, out_newemb);
}

// Round 5
// 892.772 us; speedup vs baseline: 3.3211x; 1.0059x over previous
//
#include <hip/hip_runtime.h>

// Problem constants
#define B_    64
#define C_    256
#define H_    32
#define W_    32
#define K_    1024
#define D_    256
#define HW_   1024
#define N_    65536
#define NELEM 16777216
#define DECAY_ 0.99f
#define OMD_   0.01f
#define EPS_   1e-5f
#define TAU_   0.05f        // fp64-rescan margin

// d_out float offsets
#define OFF_LOSS    16777216
#define OFF_ENT     16777217
#define OFF_ENC     16777218   // 8B-aligned only
#define OFF_CLUSTER 83886082
#define OFF_NEWW    83887106
#define OFF_NEWEMB  84149250

// Scratch inside the (later overwritten) encodings output region [OFF_ENC, OFF_ENC+67108864):
#define OFF_XHI     (OFF_ENC + 2)              // 16B-aligned; bf16 hi of -2x, [N][D] ushort
#define OFF_XLO     (OFF_XHI + 8388608)
#define OFF_EHI     (OFF_XLO + 8388608)        // bf16 hi of emb, [K][D] ushort
#define OFF_ELO     (OFF_EHI + 131072)
#define OFF_SORT2   (OFF_ELO + 131072)         // sorted[65536] | offsets[1025] | cursor[1024]

typedef __attribute__((ext_vector_type(8)))  short short8;
typedef __attribute__((ext_vector_type(16))) float floatx16;

__device__ __forceinline__ unsigned short f2bf(float f) {
    unsigned u = __float_as_uint(f);
    return (unsigned short)((u + 0x7fffu + ((u >> 16) & 1u)) >> 16);
}
__device__ __forceinline__ float bf2f(unsigned short h) {
    return __uint_as_float(((unsigned)h) << 16);
}

__global__ __launch_bounds__(256) void k_zero(float* __restrict__ dw, int* __restrict__ small_) {
    int g = blockIdx.x * 256 + threadIdx.x;
    dw[g] = 0.0f;                  // grid 1024*256 == 262144 == K*D exactly
    if (g < 1026) small_[g] = 0;   // counts[1024] + flagcount + losssum
}

// emb -> bf16 hi/lo + enorm
__global__ __launch_bounds__(64) void k_prep_e(const float* __restrict__ emb,
                                               unsigned short* __restrict__ ehi,
                                               unsigned short* __restrict__ elo,
                                               float* __restrict__ enorm) {
    const int k = blockIdx.x;
    const int t = threadIdx.x;
    float4 v = ((const float4*)(emb + (size_t)k * D_))[t];
    float s = v.x * v.x + v.y * v.y + v.z * v.z + v.w * v.w;
    ushort4 hi, lo;
    {
        float f[4] = {v.x, v.y, v.z, v.w};
        unsigned short h[4], l[4];
        #pragma unroll
        for (int j = 0; j < 4; ++j) {
            h[j] = f2bf(f[j]);
            l[j] = f2bf(f[j] - bf2f(h[j]));
        }
        hi = make_ushort4(h[0], h[1], h[2], h[3]);
        lo = make_ushort4(l[0], l[1], l[2], l[3]);
    }
    *(ushort4*)(ehi + (size_t)k * D_ + t * 4) = hi;
    *(ushort4*)(elo + (size_t)k * D_ + t * 4) = lo;
    #pragma unroll
    for (int off = 32; off > 0; off >>= 1) s += __shfl_down(s, off);
    if (t == 0) enorm[k] = s;
}

// NCHW -> n-major bf16 hi/lo split of (-2x). Tile 32 d x 256 n per block.
__global__ __launch_bounds__(256) void k_prep_x(const float* __restrict__ inp,
                                                unsigned short* __restrict__ xhi,
                                                unsigned short* __restrict__ xlo) {
    __shared__ float tile[32][257];
    const int tid = threadIdx.x;
    const int bid = blockIdx.x;            // 2048 blocks: b(64) x hwtile(4) x dtile(8)
    const int dt = bid & 7;
    const int ht = (bid >> 3) & 3;
    const int b = bid >> 5;
    const int d0 = dt * 32;
    const int hw0 = ht * 256;
    const float* src = inp + (size_t)b * (C_ * HW_) + (size_t)d0 * HW_ + hw0;
    #pragma unroll
    for (int i = 0; i < 8; ++i) {
        int idx4 = i * 256 + tid;
        int dl = idx4 >> 6;
        int nl4 = (idx4 & 63) * 4;
        float4 v = *(const float4*)(src + (size_t)dl * HW_ + nl4);
        tile[dl][nl4] = v.x; tile[dl][nl4 + 1] = v.y;
        tile[dl][nl4 + 2] = v.z; tile[dl][nl4 + 3] = v.w;
    }
    __syncthreads();
    const int nbase = b * HW_ + hw0;
    #pragma unroll
    for (int i = 0; i < 4; ++i) {
        int f8 = i * 256 + tid;            // 1024 items of 8 d
        int nl = f8 >> 2;
        int dpos = (f8 & 3) * 8;
        union { unsigned short u[8]; short8 v; } ph, pl;
        #pragma unroll
        for (int j = 0; j < 8; ++j) {
            float f = -2.0f * tile[dpos + j][nl];
            unsigned short h = f2bf(f);
            ph.u[j] = h;
            pl.u[j] = f2bf(f - bf2f(h));
        }
        size_t o = (size_t)(nbase + nl) * D_ + d0 + dpos;
        *(short8*)(xhi + o) = ph.v;
        *(short8*)(xlo + o) = pl.v;
    }
}

// MFMA bf16x3 distance argmin on 32x32x16: 32 rows/wave, 32 cols/K-step,
// 2 independent acc chains (hh, correction), per-lane tracking of 16 rows x 1 col.
__global__ __launch_bounds__(256, 2) void k_argmin(
    const unsigned short* __restrict__ xhi, const unsigned short* __restrict__ xlo,
    const unsigned short* __restrict__ ehi, const unsigned short* __restrict__ elo,
    const float* __restrict__ enorm, int* __restrict__ idx_out,
    int* __restrict__ flagcount, int* __restrict__ flaglist)
{
    const int tid = threadIdx.x;
    const int w = tid >> 6;
    const int lane = tid & 63;
    const int c32 = lane & 31;
    const int h = lane >> 5;
    const int r0 = blockIdx.x * 128 + w * 32;

    // A fragments: row m = lane&31, k = h*8 + j within each 16-chunk
    short8 Ahi[16], Alo[16];
    {
        const unsigned short* pa = xhi + (size_t)(r0 + c32) * D_ + h * 8;
        const unsigned short* pl = xlo + (size_t)(r0 + c32) * D_ + h * 8;
        #pragma unroll
        for (int ds = 0; ds < 16; ++ds) {
            Ahi[ds] = *(const short8*)(pa + ds * 16);
            Alo[ds] = *(const short8*)(pl + ds * 16);
        }
    }

    float b1[16], b2[16];
    int bi[16];
    #pragma unroll
    for (int i = 0; i < 16; ++i) { b1[i] = 3.0e38f; b2[i] = 3.0e38f; bi[i] = 0; }

    for (int ct = 0; ct < K_; ct += 32) {
        const int col = ct + c32;
        const float en = enorm[col];
        floatx16 hh, cr;
        #pragma unroll
        for (int i = 0; i < 16; ++i) { hh[i] = 0.0f; cr[i] = 0.0f; }
        const unsigned short* pbh = ehi + (size_t)col * D_ + h * 8;
        const unsigned short* pbl = elo + (size_t)col * D_ + h * 8;
        #pragma unroll
        for (int ds = 0; ds < 16; ++ds) {
            short8 bh = *(const short8*)(pbh + ds * 16);
            short8 bl = *(const short8*)(pbl + ds * 16);
            hh = __builtin_amdgcn_mfma_f32_32x32x16_bf16(Ahi[ds], bh, hh, 0, 0, 0);
            cr = __builtin_amdgcn_mfma_f32_32x32x16_bf16(Ahi[ds], bl, cr, 0, 0, 0);
            cr = __builtin_amdgcn_mfma_f32_32x32x16_bf16(Alo[ds], bh, cr, 0, 0, 0);
        }
        #pragma unroll
        for (int r = 0; r < 16; ++r) {
            float v = hh[r] + cr[r] + en;
            bool lt = v < b1[r];
            float nb2 = lt ? b1[r] : fminf(v, b2[r]);   // med3(v, b1, b2)
            b2[r] = nb2;
            b1[r] = lt ? v : b1[r];
            bi[r] = lt ? col : bi[r];
        }
    }

    // reduce each reg's (b1,b2,bi) across the 32 lanes sharing that row (c bits 0..4)
    #pragma unroll
    for (int r = 0; r < 16; ++r) {
        float B1 = b1[r], B2 = b2[r];
        int Bi = bi[r];
        #pragma unroll
        for (int mask = 1; mask <= 16; mask <<= 1) {
            float v1 = __shfl_xor(B1, mask);
            float v2 = __shfl_xor(B2, mask);
            int i1 = __shfl_xor(Bi, mask);
            if (v1 < B1 || (v1 == B1 && i1 < Bi)) {
                B2 = fminf(fminf(B1, B2), v2);
                B1 = v1; Bi = i1;
            } else {
                B2 = fminf(B2, fminf(v1, v2));
            }
        }
        if (c32 == 0) {
            int row = r0 + (r & 3) + 4 * h + 8 * (r >> 2);
            idx_out[row] = Bi;
            if (B2 - B1 < TAU_) {
                int p = atomicAdd(flagcount, 1);
                flaglist[p] = row;
            }
        }
    }
}

// Exact fp64 rescan of flagged (near-tie) rows.
__global__ __launch_bounds__(256) void k_rescan(
    const float* __restrict__ inp, const float* __restrict__ emb,
    const int* __restrict__ flagcount, const int* __restrict__ flaglist,
    int* __restrict__ idx_out)
{
    __shared__ double xd[256];
    __shared__ double sv[256];
    __shared__ int si[256];
    const int tid = threadIdx.x;
    const int nflag = *flagcount;
    for (int f = blockIdx.x; f < nflag; f += gridDim.x) {
        int n = flaglist[f];
        int b = n >> 10, nn = n & 1023;
        xd[tid] = (double)inp[(size_t)b * (C_ * HW_) + (size_t)tid * HW_ + nn];
        __syncthreads();
        double bv = 1e300; int bi = 0;
        for (int k = tid; k < K_; k += 256) {
            const float* ep = emb + (size_t)k * D_;
            double dot = 0.0, en = 0.0;
            for (int d = 0; d < D_; ++d) {
                double e = (double)ep[d];
                dot = fma(xd[d], e, dot);
                en  = fma(e, e, en);
            }
            double v = en - 2.0 * dot;
            if (v < bv) { bv = v; bi = k; }
        }
        sv[tid] = bv; si[tid] = bi;
        __syncthreads();
        for (int s = 128; s > 0; s >>= 1) {
            if (tid < s) {
                if (sv[tid + s] < sv[tid] || (sv[tid + s] == sv[tid] && si[tid + s] < si[tid])) {
                    sv[tid] = sv[tid + s]; si[tid] = si[tid + s];
                }
            }
            __syncthreads();
        }
        if (tid == 0) idx_out[n] = si[0];
        __syncthreads();
    }
}

__global__ __launch_bounds__(256) void k_hist(const int* __restrict__ idx, int* __restrict__ counts) {
    __shared__ int h[1024];
    const int tid = threadIdx.x;
    #pragma unroll
    for (int j = 0; j < 4; ++j) h[tid + j * 256] = 0;
    __syncthreads();
    #pragma unroll
    for (int j = 0; j < 4; ++j) {
        int n = blockIdx.x * 1024 + j * 256 + tid;
        atomicAdd(&h[idx[n]], 1);
    }
    __syncthreads();
    #pragma unroll
    for (int j = 0; j < 4; ++j) {
        int v = h[tid + j * 256];
        if (v) atomicAdd(&counts[tid + j * 256], v);
    }
}

__global__ __launch_bounds__(1024) void k_scan(const int* __restrict__ counts,
                                               int* __restrict__ offsets, int* __restrict__ cursor) {
    __shared__ int s[1024];
    const int t = threadIdx.x;
    const int c = counts[t];
    s[t] = c;
    __syncthreads();
    for (int off = 1; off < 1024; off <<= 1) {
        int v = (t >= off) ? s[t - off] : 0;
        __syncthreads();
        s[t] += v;
        __syncthreads();
    }
    int excl = s[t] - c;
    offsets[t] = excl;
    cursor[t] = excl;
    if (t == 1023) offsets[1024] = s[1023];
}

// Block-aggregated scatter.
__global__ __launch_bounds__(256) void k_scatter(const int* __restrict__ idx,
                                                 int* __restrict__ cursor, int* __restrict__ sorted) {
    __shared__ int hc[1024];
    __shared__ int hb[1024];
    const int tid = threadIdx.x;
    const int base = blockIdx.x * 1024;
    #pragma unroll
    for (int j = 0; j < 4; ++j) hc[tid + j * 256] = 0;
    __syncthreads();
    int myk[4], myn[4];
    #pragma unroll
    for (int j = 0; j < 4; ++j) {
        int n = base + j * 256 + tid;
        myn[j] = n;
        myk[j] = idx[n];
        atomicAdd(&hc[myk[j]], 1);
    }
    __syncthreads();
    #pragma unroll
    for (int j = 0; j < 4; ++j) {
        int kk = tid + j * 256;
        int c = hc[kk];
        hb[kk] = c ? atomicAdd(&cursor[kk], c) : 0;
    }
    __syncthreads();
    #pragma unroll
    for (int j = 0; j < 4; ++j) hc[tid + j * 256] = 0;
    __syncthreads();
    #pragma unroll
    for (int j = 0; j < 4; ++j) {
        int p = hb[myk[j]] + atomicAdd(&hc[myk[j]], 1);
        sorted[p] = myn[j];
    }
}

// Balanced segmented dw reduction reading xhi/xlo (x = -0.5*(hi+lo), exact to 2^-18).
__global__ __launch_bounds__(256) void k_dwg(const unsigned short* __restrict__ xhi,
                                             const unsigned short* __restrict__ xlo,
                                             const int* __restrict__ sorted,
                                             const int* __restrict__ idx,
                                             const int* __restrict__ offsets,
                                             float* __restrict__ dw) {
    const int lane = threadIdx.x & 63;
    const int wid = threadIdx.x >> 6;
    const int wbase = (blockIdx.x * 4 + wid) * 64;

    int myn = sorted[wbase + lane];
    int myk = idx[myn];

    float4 acc = make_float4(0.f, 0.f, 0.f, 0.f);
    int cur = __shfl(myk, 0);

    #pragma unroll 8
    for (int i = 0; i < 64; ++i) {
        int n = __shfl(myn, i);
        int k = __shfl(myk, i);
        if (k != cur) {
            bool full = (offsets[cur] >= wbase) && (offsets[cur + 1] <= wbase + 64);
            float* dwk = dw + (size_t)cur * D_ + lane * 4;
            if (full) {
                ((float2*)dwk)[0] = make_float2(-0.5f * acc.x, -0.5f * acc.y);
                ((float2*)dwk)[1] = make_float2(-0.5f * acc.z, -0.5f * acc.w);
            } else {
                atomicAdd(dwk + 0, -0.5f * acc.x);
                atomicAdd(dwk + 1, -0.5f * acc.y);
                atomicAdd(dwk + 2, -0.5f * acc.z);
                atomicAdd(dwk + 3, -0.5f * acc.w);
            }
            acc = make_float4(0.f, 0.f, 0.f, 0.f);
            cur = k;
        }
        size_t o = (size_t)n * D_ + lane * 4;
        ushort4 hx = *(const ushort4*)(xhi + o);
        ushort4 lx = *(const ushort4*)(xlo + o);
        acc.x += bf2f(hx.x) + bf2f(lx.x);
        acc.y += bf2f(hx.y) + bf2f(lx.y);
        acc.z += bf2f(hx.z) + bf2f(lx.z);
        acc.w += bf2f(hx.w) + bf2f(lx.w);
    }
    {
        bool full = (offsets[cur] >= wbase) && (offsets[cur + 1] <= wbase + 64);
        float* dwk = dw + (size_t)cur * D_ + lane * 4;
        if (full) {
            ((float2*)dwk)[0] = make_float2(-0.5f * acc.x, -0.5f * acc.y);
            ((float2*)dwk)[1] = make_float2(-0.5f * acc.z, -0.5f * acc.w);
        } else {
            atomicAdd(dwk + 0, -0.5f * acc.x);
            atomicAdd(dwk + 1, -0.5f * acc.y);
            atomicAdd(dwk + 2, -0.5f * acc.z);
            atomicAdd(dwk + 3, -0.5f * acc.w);
        }
    }
}

// encodings zero-fill, float4 (region is 8B-aligned; +2 floats is 16B-aligned)
__global__ __launch_bounds__(256) void k_enc0(float* __restrict__ enc) {
    const float4 z = make_float4(0.f, 0.f, 0.f, 0.f);
    float4* p = (float4*)(enc + 2);
    int t = blockIdx.x * 256 + threadIdx.x;
    #pragma unroll
    for (int it = 0; it < 4; ++it) {
        int i = it * 4194304 + t;
        if (i < 16777215) p[i] = z;
    }
    if (t == 0) { enc[0] = 0.f; enc[1] = 0.f; enc[67108862] = 0.f; enc[67108863] = 0.f; }
}

__global__ __launch_bounds__(256) void k_enc1(const int* __restrict__ idx, float* __restrict__ enc) {
    #pragma unroll
    for (int j = 0; j < 4; ++j) {
        int n = blockIdx.x * 1024 + j * 256 + threadIdx.x;
        enc[(size_t)n * 1024 + idx[n]] = 1.0f;
    }
}

__global__ __launch_bounds__(256) void k_quant(
    const float* __restrict__ inp, const float* __restrict__ emb,
    const int* __restrict__ idx, float* __restrict__ outp, float* __restrict__ losssum)
{
    __shared__ float red[256];
    const int tid = threadIdx.x;
    float s = 0.0f;
    const int base = blockIdx.x * 1024;
    #pragma unroll
    for (int it = 0; it < 4; ++it) {
        int g = base + it * 256 + tid;
        int o = g << 2;
        int b = o >> 18;
        int c = (o >> 10) & 255;
        int hw = o & 1023;
        int n = (b << 10) + hw;
        float4 x = ((const float4*)inp)[g];
        int4 ki = *(const int4*)(idx + n);
        float q0 = emb[(size_t)ki.x * D_ + c];
        float q1 = emb[(size_t)ki.y * D_ + c];
        float q2 = emb[(size_t)ki.z * D_ + c];
        float q3 = emb[(size_t)ki.w * D_ + c];
        float d0 = q0 - x.x, d1 = q1 - x.y, d2 = q2 - x.z, d3 = q3 - x.w;
        ((float4*)outp)[g] = make_float4(x.x + d0, x.y + d1, x.z + d2, x.w + d3);
        s += d0 * d0 + d1 * d1 + d2 * d2 + d3 * d3;
    }
    red[tid] = s;
    __syncthreads();
    for (int t = 128; t > 0; t >>= 1) {
        if (tid < t) red[tid] += red[tid + t];
        __syncthreads();
    }
    if (tid == 0) atomicAdd(losssum, red[0]);
}

__global__ __launch_bounds__(1024) void k_cluster(
    const float* __restrict__ ema_cs, const int* __restrict__ counts,
    const float* __restrict__ losssum, float* __restrict__ out_cluster,
    float* __restrict__ out_loss, float* __restrict__ out_ent)
{
    __shared__ float red[1024];
    const int k = threadIdx.x;
    float cnt = (float)counts[k];
    float raw = ema_cs[k] * DECAY_ + OMD_ * cnt;
    red[k] = raw;
    __syncthreads();
    for (int t = 512; t > 0; t >>= 1) {
        if (k < t) red[k] += red[k + t];
        __syncthreads();
    }
    float nsum = red[0];
    __syncthreads();
    float clv = (raw + EPS_) / (nsum + 1024.0f * EPS_) * nsum;
    out_cluster[k] = clv;
    float p = cnt * (1.0f / 65536.0f);
    red[k] = p * logf(p + 1e-10f);
    __syncthreads();
    for (int t = 512; t > 0; t >>= 1) {
        if (k < t) red[k] += red[k + t];
        __syncthreads();
    }
    if (k == 0) {
        out_ent[0] = -red[0];
        out_loss[0] = 0.25f * losssum[0] * (1.0f / 16777216.0f);
    }
}

__global__ __launch_bounds__(256) void k_fin(
    const float* __restrict__ ema_w, const float* __restrict__ cluster,
    float* __restrict__ neww, float* __restrict__ newemb)
{
    int g = blockIdx.x * 256 + threadIdx.x;
    int k = g >> 8;
    float w = ema_w[g] * DECAY_ + OMD_ * neww[g];   // neww currently holds dw
    neww[g] = w;
    newemb[g] = w / cluster[k];
}

extern "C" void kernel_launch(void* const* d_in, const int* in_sizes, int n_in,
                              void* d_out, int out_size, void* d_ws, size_t ws_size,
                              hipStream_t stream)
{
    const float* inp    = (const float*)d_in[0];
    const float* emb    = (const float*)d_in[1];
    const float* ema_cs = (const float*)d_in[2];
    const float* ema_w  = (const float*)d_in[3];

    float* out0        = (float*)d_out;
    float* out_loss    = out0 + OFF_LOSS;
    float* out_ent     = out0 + OFF_ENT;
    float* out_enc     = out0 + OFF_ENC;
    float* out_cluster = out0 + OFF_CLUSTER;
    float* out_neww    = out0 + OFF_NEWW;
    float* out_newemb  = out0 + OFF_NEWEMB;

    unsigned short* ws_xhi  = (unsigned short*)(out0 + OFF_XHI);
    unsigned short* ws_xlo  = (unsigned short*)(out0 + OFF_XLO);
    unsigned short* ws_ehi  = (unsigned short*)(out0 + OFF_EHI);
    unsigned short* ws_elo  = (unsigned short*)(out0 + OFF_ELO);
    int*   ws_sorted  = (int*)(out0 + OFF_SORT2);
    int*   ws_offsets = ws_sorted + 65536;
    int*   ws_cursor  = ws_offsets + 1025;

    int*   ws_idx    = (int*)d_ws;
    int*   ws_counts = ws_idx + 65536;
    int*   ws_flagc  = ws_idx + 66560;
    float* ws_loss   = (float*)(ws_idx + 66561);
    int*   ws_flagl  = ws_idx + 66562;
    float* ws_enorm  = (float*)(ws_idx + 132098);

    k_zero   <<<1024, 256, 0, stream>>>(out_neww, ws_counts);
    k_prep_e <<<1024, 64, 0, stream>>>(emb, ws_ehi, ws_elo, ws_enorm);
    k_prep_x <<<2048, 256, 0, stream>>>(inp, ws_xhi, ws_xlo);
    k_argmin <<<512, 256, 0, stream>>>(ws_xhi, ws_xlo, ws_ehi, ws_elo, ws_enorm,
                                       ws_idx, ws_flagc, ws_flagl);
    k_rescan <<<256, 256, 0, stream>>>(inp, emb, ws_flagc, ws_flagl, ws_idx);
    k_hist   <<<64, 256, 0, stream>>>(ws_idx, ws_counts);
    k_scan   <<<1, 1024, 0, stream>>>(ws_counts, ws_offsets, ws_cursor);
    k_scatter<<<64, 256, 0, stream>>>(ws_idx, ws_cursor, ws_sorted);
    k_dwg    <<<256, 256, 0, stream>>>(ws_xhi, ws_xlo, ws_sorted, ws_idx, ws_offsets, out_neww);
    k_enc0   <<<16384, 256, 0, stream>>>(out_enc);
    k_enc1   <<<64, 256, 0, stream>>>(ws_idx, out_enc);
    k_quant  <<<4096, 256, 0, stream>>>(inp, emb, ws_idx, out0, ws_loss);
    k_cluster<<<1, 1024, 0, stream>>>(ema_cs, ws_counts, ws_loss, out_cluster, out_loss, out_ent);
    k_fin    <<<1024, 256, 0, stream>>>(ema_w, out_cluster, out_neww, out_newemb);
}